// Round 1
// 512.330 us; speedup vs baseline: 1.0156x; 1.0156x over previous
//
#include <hip/hip_runtime.h>
#include <hip/hip_bf16.h>
#include <math.h>

// ---------------- static problem config ----------------
#define BB 4
#define LL 4096
#define DD 1024
#define KK 32
#define HH 32
#define AA 4
#define CKK 4
#define DI 1024
#define ZC 2080            // 2*DI + KK
#define FLATC 1024         // K*H
#define BL (BB * LL)       // 16384
#define ZLD 2080           // z row stride (bf16)
#define NPAD 2176          // W_in^T padded rows (17*128)

// scan config
#define CH 256
#define NCH (LL / CH)      // 16

// norm_head LDS strides (skewed to break lq-stride-128 bank conflicts)
#define GLD 1136           // zw row stride in u16 : col = o + (o>>7)*16
#define KLD 1080           // skern row stride in f32: col = o + (o>>7)*8

typedef unsigned short u16;
typedef __attribute__((ext_vector_type(8))) short s16x8;
typedef __attribute__((ext_vector_type(4))) float f32x4;

__device__ __forceinline__ u16 f2bf(float f) {
  union { float f; unsigned int u; } v; v.f = f;
  unsigned int r = (v.u + 0x7FFFu + ((v.u >> 16) & 1u)) >> 16;
  return (u16)r;
}
__device__ __forceinline__ float bf2f(u16 u) {
  union { unsigned int i; float f; } x; x.i = ((unsigned int)u) << 16; return x.f;
}
__device__ __forceinline__ void gl_lds16(const void* g, void* l) {
  __builtin_amdgcn_global_load_lds(
      (const __attribute__((address_space(1))) unsigned int*)g,
      (__attribute__((address_space(3))) unsigned int*)l, 16, 0, 0);
}

// ---------------- cast f32 -> bf16 (x) ----------------
__global__ __launch_bounds__(256) void cast_bf16_kernel(
    const float* __restrict__ src, u16* __restrict__ dst, int n) {
  const int i = (blockIdx.x * 256 + threadIdx.x) * 8;
  if (i >= n) return;
  float4 a = *(const float4*)(src + i);
  float4 b = *(const float4*)(src + i + 4);
  s16x8 v;
  v[0] = (short)f2bf(a.x); v[1] = (short)f2bf(a.y);
  v[2] = (short)f2bf(a.z); v[3] = (short)f2bf(a.w);
  v[4] = (short)f2bf(b.x); v[5] = (short)f2bf(b.y);
  v[6] = (short)f2bf(b.z); v[7] = (short)f2bf(b.w);
  *(s16x8*)(dst + i) = v;
}

// ---------------- transpose + cast: src[R][C] f32 -> dst[Cpad][R] bf16 ----
__global__ __launch_bounds__(256) void transpose_cast_kernel(
    const float* __restrict__ src, u16* __restrict__ dst,
    int R, int C, int Cpad) {
  __shared__ float t[32][33];
  const int tid = threadIdx.x;
  const int r0 = blockIdx.x * 32, c0 = blockIdx.y * 32;
  const int lr = tid >> 5, lc = tid & 31;
#pragma unroll
  for (int i = 0; i < 4; ++i) {
    const int r = r0 + i * 8 + lr, c = c0 + lc;
    float v = 0.f;
    if (r < R && c < C) v = src[(size_t)r * C + c];
    t[lc][i * 8 + lr] = v;
  }
  __syncthreads();
#pragma unroll
  for (int i = 0; i < 4; ++i) {
    const int dr = c0 + i * 8 + lr;   // row in dst = col in src
    const int dc = r0 + lc;           // col in dst = row in src
    if (dr < Cpad && dc < R) dst[(size_t)dr * R + dc] = f2bf(t[i * 8 + lr][lc]);
  }
}

// ---------------- bf16 MFMA GEMM: C[M,N] = A[M,K] * Bt[N,K]^T -------------
// 128x128 tile, 4 waves in 2x2, 16x16x32 MFMA, BK=64, global_load_lds(16B).
// 2-phase double-buffered pipeline (guide T3 minimum recipe): issue the
// next K-tile's global_load_lds into buf^1 BEFORE computing the current
// tile from buf; a single __syncthreads() per K-step (its vmcnt(0) drain
// lands after the MFMA work, hiding the staging latency under compute).
// Dispatch swizzle: blockIdx.x = ROW tile (fast-varying), blockIdx.y = COL
// tile. Same-row blocks are spaced by gridDim.x (multiple of 8) -> same XCD
// under round-robin dispatch, so the A row-stripe stays in that XCD's L2
// across all column tiles.
template <int OUT_BF16>
__global__ __launch_bounds__(256) void gemm_bf16_mfma(
    const u16* __restrict__ A, const u16* __restrict__ Bt, void* __restrict__ C,
    int lda, int ldb, int ldc, int Kd, int Ncols) {
  __shared__ u16 As[2][8192];   // dbuf x 16 blocks x 512 elems
  __shared__ u16 Bs[2][8192];
  const int tid = threadIdx.x;
  const int lane = tid & 63, wv = tid >> 6;
  const int lm = lane & 15, lq = lane >> 4;
  const int bm = blockIdx.x * 128, bn = blockIdx.y * 128;
  const int wrow = (wv & 1) * 64, wcol = (wv >> 1) * 64;

  // stage one K-tile (k0) into buffer `buf`: each wave issues 8x 1KB loads
  auto stage = [&](int k0, int buf) {
#pragma unroll
    for (int t = 0; t < 8; ++t) {
      const int idx = wv * 8 + t;             // 0..31
      if (idx < 16) {                          // A block (mt, kt)
        const int mt = idx >> 1, kt = idx & 1;
        const u16* g = A + (size_t)(bm + mt * 16 + lm) * lda + k0 + kt * 32 + lq * 8;
        gl_lds16(g, &As[buf][idx * 512]);
      } else {                                 // B block (nt, kt)
        const int bidx = idx - 16;
        const int nt = bidx >> 1, kt = bidx & 1;
        const u16* g = Bt + (size_t)(bn + nt * 16 + lm) * ldb + k0 + kt * 32 + lq * 8;
        gl_lds16(g, &Bs[buf][bidx * 512]);
      }
    }
  };

  const f32x4 z4 = {0.f, 0.f, 0.f, 0.f};
  f32x4 acc[4][4];
#pragma unroll
  for (int i = 0; i < 4; ++i)
#pragma unroll
    for (int j = 0; j < 4; ++j) acc[i][j] = z4;

  // prologue: stage tile 0 into buffer 0
  stage(0, 0);
  __syncthreads();

  int cur = 0;
  for (int k0 = 0; k0 < Kd; k0 += 64) {
    // issue next tile's loads into the other buffer (overlaps with compute)
    if (k0 + 64 < Kd) stage(k0 + 64, cur ^ 1);

#pragma unroll
    for (int kt = 0; kt < 2; ++kt) {
      s16x8 af[4], bfb[4];
#pragma unroll
      for (int i = 0; i < 4; ++i) {
        const int mt = (wrow >> 4) + i;
        af[i] = *(const s16x8*)&As[cur][(mt * 2 + kt) * 512 + lane * 8];
        const int nt = (wcol >> 4) + i;
        bfb[i] = *(const s16x8*)&Bs[cur][(nt * 2 + kt) * 512 + lane * 8];
      }
#pragma unroll
      for (int i = 0; i < 4; ++i)
#pragma unroll
        for (int j = 0; j < 4; ++j)
          acc[i][j] = __builtin_amdgcn_mfma_f32_16x16x32_bf16(af[i], bfb[j], acc[i][j], 0, 0, 0);
    }
    // one barrier per K-step: drains vmcnt(0) (next tile landed) and syncs
    // all waves' LDS reads of `cur` before it is overwritten next step.
    __syncthreads();
    cur ^= 1;
  }
  // epilogue: C/D layout col = lane&15, row = (lane>>4)*4 + reg
#pragma unroll
  for (int i = 0; i < 4; ++i) {
#pragma unroll
    for (int j = 0; j < 4; ++j) {
#pragma unroll
      for (int r = 0; r < 4; ++r) {
        const int row = bm + wrow + i * 16 + lq * 4 + r;
        const int col = bn + wcol + j * 16 + lm;
        if (col < Ncols) {
          if (OUT_BF16)
            ((u16*)C)[(size_t)row * ldc + col] = f2bf(acc[i][j][r]);
          else
            ((float*)C)[(size_t)row * ldc + col] = acc[i][j][r];
        }
      }
    }
  }
}

// ---------------- conv + p_w + phase features (reads z bf16) --------------
__global__ __launch_bounds__(256) void conv_feat_kernel(
    const u16* __restrict__ z, const float* __restrict__ kern,
    const float* __restrict__ theta, const float* __restrict__ decay,
    const float* __restrict__ anchor, const float* __restrict__ sscale,
    float* __restrict__ merged) {
  __shared__ u16 zw[11 * ZLD];    // 45760 B
  __shared__ float spw[8][32];
  const int tid = threadIdx.x;
  const int r0 = blockIdx.x * 8;
  const bool first = ((r0 & (LL - 1)) == 0);

  for (int idx = tid; idx < 11 * (ZLD / 8); idx += 256) {
    const int i = idx / (ZLD / 8);
    const int c8 = idx - i * (ZLD / 8);
    s16x8 v = {0, 0, 0, 0, 0, 0, 0, 0};
    if (!(first && i < 3))
      v = *(const s16x8*)(z + (size_t)(r0 - 3 + i) * ZLD + c8 * 8);
    *(s16x8*)&zw[i * ZLD + c8 * 8] = v;
  }
  __syncthreads();

  {  // scores -> p_w (8 rows x 32 heads = 256 threads)
    const int rr = tid >> 5, k = tid & 31;
    float v = 0.f;
#pragma unroll
    for (int w = 0; w < CKK; ++w)
      v = fmaf(bf2f(zw[(rr + w) * ZLD + 2048 + k]), kern[w * ZC + 2048 + k], v);
    const int l = (r0 + rr) & (LL - 1);
    const float slope = (k < KK - AA) ? decay[k] : anchor[k - (KK - AA)];
    const float sp = log1pf(__expf(slope));
    const float lw = (k < KK - AA) ? (-sp * (float)(LL - 1 - l)) : (-sp * (float)l);
    const float p = __expf(sscale[k] * v + lw);
    spw[rr][k] = p;
    merged[(size_t)(r0 + rr) * ZC + k] = p;
  }
  __syncthreads();

#pragma unroll 1
  for (int it = 0; it < 4; ++it) {
    const int c = it * 256 + tid;   // 0..1023
    const float kw0 = kern[0 * ZC + c], kw1 = kern[1 * ZC + c];
    const float kw2 = kern[2 * ZC + c], kw3 = kern[3 * ZC + c];
    const float th = theta[c];
    float zv[11];
#pragma unroll
    for (int i = 0; i < 11; ++i) zv[i] = bf2f(zw[i * ZLD + c]);
#pragma unroll
    for (int rr = 0; rr < 8; ++rr) {
      float v = zv[rr] * kw0;
      v = fmaf(zv[rr + 1], kw1, v);
      v = fmaf(zv[rr + 2], kw2, v);
      v = fmaf(zv[rr + 3], kw3, v);
      const float phi = v * th;
      float sv, cv;
      __sincosf(phi, &sv, &cv);
      const float p = spw[rr][c >> 5];
      float* mrow = merged + (size_t)(r0 + rr) * ZC;
      mrow[KK + c] = p * cv;
      mrow[KK + FLATC + c] = p * sv;
    }
  }
}

// ---------------- blocked scan over L ----------------
__global__ __launch_bounds__(256) void scan_partial_kernel(
    const float* __restrict__ merged, float* __restrict__ part) {
  const int c = blockIdx.x * 256 + threadIdx.x;
  const int chunk = blockIdx.y, b = blockIdx.z;
  if (c >= ZC) return;
  size_t base = ((size_t)b * LL + (size_t)chunk * CH) * ZC + c;
  float s = 0.f;
#pragma unroll 8
  for (int i = 0; i < CH; ++i) s += merged[base + (size_t)i * ZC];
  part[((size_t)b * NCH + chunk) * ZC + c] = s;
}

__global__ __launch_bounds__(256) void scan_offsets_kernel(float* __restrict__ part) {
  const int c = blockIdx.x * 256 + threadIdx.x;
  const int b = blockIdx.z;
  if (c >= ZC) return;
  float run = 0.f;
#pragma unroll
  for (int i = 0; i < NCH; ++i) {
    const size_t idx = ((size_t)b * NCH + i) * ZC + c;
    const float t = part[idx];
    part[idx] = run;
    run += t;
  }
}

__global__ __launch_bounds__(256) void scan_apply_kernel(
    float* __restrict__ merged, const float* __restrict__ part) {
  const int c = blockIdx.x * 256 + threadIdx.x;
  const int chunk = blockIdx.y, b = blockIdx.z;
  if (c >= ZC) return;
  float s = part[((size_t)b * NCH + chunk) * ZC + c];
  size_t base = ((size_t)b * LL + (size_t)chunk * CH) * ZC + c;
#pragma unroll 4
  for (int i = 0; i < CH; ++i) {
    const size_t idx = base + (size_t)i * ZC;
    s += merged[idx];
    merged[idx] = s;
  }
}

// ---------------- fold norm_scale into head weights (bf16) ----------------
__global__ __launch_bounds__(256) void wprime_kernel(
    const float* __restrict__ W_re, const float* __restrict__ W_im,
    const float* __restrict__ ns, u16* __restrict__ wp) {
  const int i = blockIdx.x * 256 + threadIdx.x;   // 0..2047
  if (i < 1024) wp[i] = f2bf(ns[i >> 5] * W_re[i]);
  else {
    const int j = i - 1024;
    wp[i] = f2bf(ns[32 + (j >> 5)] * W_im[j]);
  }
}

// ---------------- norm_head via MFMA ----------------
// Block = 8 bl rows (4 waves x 2 rows). Per (bl,k) row: scale from raw row
// sums, y = [re;im]*scale @ [Wre';Wim'] via 16x16x32 bf16 MFMA, g = y*gate
// written bf16 in-place into merged row head (den read before any write).
__global__ __launch_bounds__(256) void norm_head_mfma(
    float* merged, const u16* __restrict__ z, const float* __restrict__ kern,
    const u16* __restrict__ wp) {
  __shared__ u16 zw[11 * GLD];       // skewed gate-z tile
  __shared__ float skern[4 * KLD];   // skewed gate conv weights
  const int tid = threadIdx.x;
  const int r0 = blockIdx.x * 8;
  const bool first = ((r0 & (LL - 1)) == 0);
  const int lane = tid & 63, wv = tid >> 6;
  const int lm = lane & 15, lq = lane >> 4;

  // stage z gate cols (1024..2047), rows r0-3 .. r0+7, with skew
  for (int idx = tid; idx < 11 * 128; idx += 256) {
    const int i = idx >> 7, c8 = idx & 127;
    s16x8 v = {0, 0, 0, 0, 0, 0, 0, 0};
    if (!(first && i < 3))
      v = *(const s16x8*)(z + (size_t)(r0 - 3 + i) * ZLD + 1024 + c8 * 8);
    *(s16x8*)&zw[i * GLD + c8 * 8 + (c8 >> 4) * 16] = v;
  }
  // stage gate conv weights (f32) with skew
  for (int idx = tid; idx < 4 * 256; idx += 256) {
    const int w = idx >> 8, c4 = idx & 255;
    float4 v = *(const float4*)(kern + w * ZC + 1024 + c4 * 4);
    *(float4*)&skern[w * KLD + c4 * 4 + (c4 >> 5) * 8] = v;
  }

  // B fragments (same for all rows): lane(lm,lq) holds W'[lq*8+j][nt*16+lm]
  s16x8 bre[2], bim[2];
#pragma unroll
  for (int nt = 0; nt < 2; ++nt)
#pragma unroll
    for (int jj = 0; jj < 8; ++jj) {
      bre[nt][jj] = (short)wp[(lq * 8 + jj) * 32 + nt * 16 + lm];
      bim[nt][jj] = (short)wp[1024 + (lq * 8 + jj) * 32 + nt * 16 + lm];
    }
  __syncthreads();

  const f32x4 z4 = {0.f, 0.f, 0.f, 0.f};
#pragma unroll 1
  for (int rr2 = 0; rr2 < 2; ++rr2) {
    const int rr = wv * 2 + rr2;          // 0..7 within block
    const int bl = r0 + rr;
    float* row = merged + (size_t)bl * ZC;
    // den for BOTH k-halves, before any write to this row
    const float den0 = row[lm], den1 = row[16 + lm];

#pragma unroll
    for (int khalf = 0; khalf < 2; ++khalf) {
      // A loads: re/im for (bl, k = khalf*16+lm), hp = lq*8..lq*8+7
      const float* rp = row + KK + (khalf * 16 + lm) * 32 + lq * 8;
      float4 ra = *(const float4*)rp;
      float4 rb = *(const float4*)(rp + 4);
      float4 ia = *(const float4*)(rp + FLATC);
      float4 ib = *(const float4*)(rp + FLATC + 4);

      float ssq = ra.x * ra.x + ra.y * ra.y + ra.z * ra.z + ra.w * ra.w +
                  rb.x * rb.x + rb.y * rb.y + rb.z * rb.z + rb.w * rb.w +
                  ia.x * ia.x + ia.y * ia.y + ia.z * ia.z + ia.w * ia.w +
                  ib.x * ib.x + ib.y * ib.y + ib.z * ib.z + ib.w * ib.w;
      ssq += __shfl_xor(ssq, 16);
      ssq += __shfl_xor(ssq, 32);
      const float den = khalf ? den1 : den0;
      const float inv = 1.0f / fmaxf(den, 1e-4f);
      const float scale = inv * rsqrtf(ssq * inv * inv * (1.0f / 64.0f) + 1e-5f);

      s16x8 afr, afi;
      afr[0] = (short)f2bf(ra.x * scale); afr[1] = (short)f2bf(ra.y * scale);
      afr[2] = (short)f2bf(ra.z * scale); afr[3] = (short)f2bf(ra.w * scale);
      afr[4] = (short)f2bf(rb.x * scale); afr[5] = (short)f2bf(rb.y * scale);
      afr[6] = (short)f2bf(rb.z * scale); afr[7] = (short)f2bf(rb.w * scale);
      afi[0] = (short)f2bf(ia.x * scale); afi[1] = (short)f2bf(ia.y * scale);
      afi[2] = (short)f2bf(ia.z * scale); afi[3] = (short)f2bf(ia.w * scale);
      afi[4] = (short)f2bf(ib.x * scale); afi[5] = (short)f2bf(ib.y * scale);
      afi[6] = (short)f2bf(ib.z * scale); afi[7] = (short)f2bf(ib.w * scale);

      f32x4 acc[2];
#pragma unroll
      for (int nt = 0; nt < 2; ++nt) {
        acc[nt] = __builtin_amdgcn_mfma_f32_16x16x32_bf16(afr, bre[nt], z4, 0, 0, 0);
        acc[nt] = __builtin_amdgcn_mfma_f32_16x16x32_bf16(afi, bim[nt], acc[nt], 0, 0, 0);
      }

      // epilogue: D row = lq*4+r (k offset), col = lm (h offset)
      u16* grow = (u16*)row;
#pragma unroll
      for (int nt = 0; nt < 2; ++nt) {
#pragma unroll
        for (int r = 0; r < 4; ++r) {
          const int k = khalf * 16 + lq * 4 + r;
          const int o = k * 32 + nt * 16 + lm;
          const int sk = o + (o >> 7) * 8;    // skern skew
          const int sz = o + (o >> 7) * 16;   // zw skew
          float gv = bf2f(zw[(rr + 0) * GLD + sz]) * skern[0 * KLD + sk];
          gv = fmaf(bf2f(zw[(rr + 1) * GLD + sz]), skern[1 * KLD + sk], gv);
          gv = fmaf(bf2f(zw[(rr + 2) * GLD + sz]), skern[2 * KLD + sk], gv);
          gv = fmaf(bf2f(zw[(rr + 3) * GLD + sz]), skern[3 * KLD + sk], gv);
          const float sil = gv * (1.0f / (1.0f + __expf(-gv)));
          grow[o] = f2bf(acc[nt][r] * sil);
        }
      }
    }
  }
}

// ---------------- launch ----------------
extern "C" void kernel_launch(void* const* d_in, const int* in_sizes, int n_in,
                              void* d_out, int out_size, void* d_ws, size_t ws_size,
                              hipStream_t stream) {
  const float* x      = (const float*)d_in[0];
  const float* W_in   = (const float*)d_in[1];
  const float* kern   = (const float*)d_in[2];
  const float* theta  = (const float*)d_in[3];
  const float* decay  = (const float*)d_in[4];
  const float* anchor = (const float*)d_in[5];
  const float* sscale = (const float*)d_in[6];
  const float* W_re   = (const float*)d_in[7];
  const float* W_im   = (const float*)d_in[8];
  const float* nscale = (const float*)d_in[9];
  const float* W_out  = (const float*)d_in[10];
  float* out = (float*)d_out;

  // workspace layout (~199.8 MiB + 4 KB):
  char* w = (char*)d_ws;
  float* merged = (float*)w;
  u16* xbf = (u16*)w;                                  // alias: dead once gemm1 done
  u16* zbf = (u16*)(w + (size_t)BL * ZC * 4);
  u16* wobt = zbf;                                     // alias: written after norm_head
  u16* wbt = (u16*)(w + (size_t)BL * ZC * 4 + (size_t)BL * ZLD * 2);
  float* part = (float*)((char*)wbt + (size_t)NPAD * DD * 2);
  u16* wp = (u16*)(part + (size_t)BB * NCH * ZC);      // 2048 u16

  // 1) casts / transposes / weight fold
  cast_bf16_kernel<<<dim3(BL * DD / 8 / 256), 256, 0, stream>>>(x, xbf, BL * DD);
  transpose_cast_kernel<<<dim3(32, 68), 256, 0, stream>>>(W_in, wbt, DD, ZC, NPAD);
  wprime_kernel<<<dim3(8), 256, 0, stream>>>(W_re, W_im, nscale, wp);

  // 2) GEMM1: z = x @ W_in  (bf16 MFMA, bf16 out). grid.x = row tiles.
  gemm_bf16_mfma<1><<<dim3(BL / 128, NPAD / 128), 256, 0, stream>>>(
      xbf, wbt, zbf, DD, DD, ZLD, DD, ZC);

  // 3) conv + p_w + features -> merged
  conv_feat_kernel<<<dim3(BL / 8), 256, 0, stream>>>(zbf, kern, theta, decay,
                                                     anchor, sscale, merged);

  // 4) blocked inclusive scan over L (in-place on merged)
  {
    dim3 grid((ZC + 255) / 256, NCH, BB);
    scan_partial_kernel<<<grid, 256, 0, stream>>>(merged, part);
    dim3 grid2((ZC + 255) / 256, 1, BB);
    scan_offsets_kernel<<<grid2, 256, 0, stream>>>(part);
    scan_apply_kernel<<<grid, 256, 0, stream>>>(merged, part);
  }

  // 5) normalize + RMS + head matmuls (MFMA) + gate -> g (bf16, in-place)
  norm_head_mfma<<<dim3(BL / 8), 256, 0, stream>>>(merged, zbf, kern, wp);

  // 6) W_out^T (into dead z region), then GEMM2: out = g @ W_out (f32 out)
  transpose_cast_kernel<<<dim3(32, 32), 256, 0, stream>>>(W_out, wobt, DI, DD, DD);
  gemm_bf16_mfma<0><<<dim3(BL / 128, DD / 128), 256, 0, stream>>>(
      (const u16*)merged, wobt, out, 2 * ZC, DI, DD, DI, DD);
}

// Round 2
// 445.165 us; speedup vs baseline: 1.1689x; 1.1509x over previous
//
#include <hip/hip_runtime.h>
#include <hip/hip_bf16.h>
#include <math.h>

// ---------------- static problem config ----------------
#define BB 4
#define LL 4096
#define DD 1024
#define KK 32
#define HH 32
#define AA 4
#define CKK 4
#define DI 1024
#define ZC 2080            // 2*DI + KK
#define FLATC 1024         // K*H
#define BL (BB * LL)       // 16384
#define ZLD 2080           // z row stride (bf16)
#define NPAD 2176          // W_in^T padded rows (17*128)

// scan config
#define CH 256
#define NCH (LL / CH)      // 16

// norm_head LDS strides (skewed to break lq-stride-128 bank conflicts)
#define GLD 1136           // zw row stride in u16 : col = o + (o>>7)*16
#define KLD 1080           // skern row stride in f32: col = o + (o>>7)*8

typedef unsigned short u16;
typedef __attribute__((ext_vector_type(8))) short s16x8;
typedef __attribute__((ext_vector_type(4))) float f32x4;

__device__ __forceinline__ u16 f2bf(float f) {
  union { float f; unsigned int u; } v; v.f = f;
  unsigned int r = (v.u + 0x7FFFu + ((v.u >> 16) & 1u)) >> 16;
  return (u16)r;
}
__device__ __forceinline__ float bf2f(u16 u) {
  union { unsigned int i; float f; } x; x.i = ((unsigned int)u) << 16; return x.f;
}
__device__ __forceinline__ void gl_lds16(const void* g, void* l) {
  __builtin_amdgcn_global_load_lds(
      (const __attribute__((address_space(1))) unsigned int*)g,
      (__attribute__((address_space(3))) unsigned int*)l, 16, 0, 0);
}

// ---------------- cast f32 -> bf16 (x) ----------------
__global__ __launch_bounds__(256) void cast_bf16_kernel(
    const float* __restrict__ src, u16* __restrict__ dst, int n) {
  const int i = (blockIdx.x * 256 + threadIdx.x) * 8;
  if (i >= n) return;
  float4 a = *(const float4*)(src + i);
  float4 b = *(const float4*)(src + i + 4);
  s16x8 v;
  v[0] = (short)f2bf(a.x); v[1] = (short)f2bf(a.y);
  v[2] = (short)f2bf(a.z); v[3] = (short)f2bf(a.w);
  v[4] = (short)f2bf(b.x); v[5] = (short)f2bf(b.y);
  v[6] = (short)f2bf(b.z); v[7] = (short)f2bf(b.w);
  *(s16x8*)(dst + i) = v;
}

// ---------------- transpose + cast: src[R][C] f32 -> dst[Cpad][R] bf16 ----
__global__ __launch_bounds__(256) void transpose_cast_kernel(
    const float* __restrict__ src, u16* __restrict__ dst,
    int R, int C, int Cpad) {
  __shared__ float t[32][33];
  const int tid = threadIdx.x;
  const int r0 = blockIdx.x * 32, c0 = blockIdx.y * 32;
  const int lr = tid >> 5, lc = tid & 31;
#pragma unroll
  for (int i = 0; i < 4; ++i) {
    const int r = r0 + i * 8 + lr, c = c0 + lc;
    float v = 0.f;
    if (r < R && c < C) v = src[(size_t)r * C + c];
    t[lc][i * 8 + lr] = v;
  }
  __syncthreads();
#pragma unroll
  for (int i = 0; i < 4; ++i) {
    const int dr = c0 + i * 8 + lr;   // row in dst = col in src
    const int dc = r0 + lc;           // col in dst = row in src
    if (dr < Cpad && dc < R) dst[(size_t)dr * R + dc] = f2bf(t[i * 8 + lr][lc]);
  }
}

// ---------------- 256x256 8-phase bf16 MFMA GEMM (T1+T2+T3+T4+T5) --------
// C[M,N] = A[M,K] * Bt[N,K]^T.  512 threads = 8 waves (2M x 4N), per-wave
// output 128x64 (8x4 fragments of 16x16), BK=64, NT = K/64 tiles (even).
//
// LDS 128KB: 8 half-regions of 16KB (128 rows x 64 cols bf16, row-major,
// st_16x32 swizzle: byte ^= ((byte>>9)&1)<<5). global_load_lds writes
// LINEAR dest; the swizzle is applied by pre-swizzling the GLOBAL source
// address (involution), reads apply the same XOR (rule #21).
//
// Per K-tile reads (per wave): p+0: A(mh0) 8x b128 + B(all) 8x b128,
// p+2: A(mh1) 8x b128.  So A regions free after p+2, B after p+0.
// Stage stream (1 half/phase): p0: s1A1(T2t+1), p1: s0B0(T2t+2),
// p2: s0B1, p3: s0A0, p4: s0A1, p5: s1B0(T2t+3), p6: s1B1, p7: s1A0.
// Gates: s_waitcnt vmcnt(6) at end of p3 and p7 ONLY (3 halves = 6 loads
// allowed in flight).  Raw s_barrier + compiler fence (no __syncthreads,
// so no vmcnt(0) drain) keeps prefetch loads in flight across barriers.
#define FENCE() asm volatile("" ::: "memory")
#define SBAR() do { FENCE(); __builtin_amdgcn_s_barrier(); FENCE(); } while (0)
#define VMCNT6() asm volatile("s_waitcnt vmcnt(6)" ::: "memory")

// region u16 offsets: A(s,h) = (s*2+h)*8192 ; B(s,h) = 32768 + (s*2+h)*8192
#define RA(s, h) (((s) * 2 + (h)) * 8192)
#define RB(s, h) (32768 + ((s) * 2 + (h)) * 8192)

template <int OUT_BF16>
__global__ __launch_bounds__(512, 2) void gemm256_8ph(
    const u16* __restrict__ A, const u16* __restrict__ Bt, void* __restrict__ C,
    int lda, int ldb, int ldc, int Kd, int Ncols) {
  __shared__ u16 lds[65536];   // 128 KiB
  const int tid = threadIdx.x;
  const int lane = tid & 63, wv = tid >> 6;
  const int wm = wv >> 2, wn = wv & 3;       // 2M x 4N wave grid
  const int lm = lane & 15, lq = lane >> 4;
  const int bm = blockIdx.x * 256, bn = blockIdx.y * 256;
  const int NT = Kd >> 6;                    // K tiles (even)
  const int NT2 = NT >> 1;

  // staging: per wave per call, 2x global_load_lds(16B) cover one 16KB
  // half-region (128 rows x 128B). LDS dest linear: j*8192 + wv*1024 +
  // lane*16. Pre-swizzled global source (xor of byte-bit5 with bit9):
  const int rofs = wv * 8 + (lane >> 3);                       // region row
  const int cel = ((lane & 7) * 8) ^ ((lane & 32) ? 16 : 0);   // col elems

  auto stageH = [&](const u16* __restrict__ G, int rowBase, int ld, int kt,
                    int regU16) {
    const u16* g0 = G + (size_t)(rowBase + rofs) * ld + (kt << 6) + cel;
    gl_lds16(g0, &lds[regU16 + wv * 512]);
    const u16* g1 = G + (size_t)(rowBase + 64 + rofs) * ld + (kt << 6) + cel;
    gl_lds16(g1, &lds[regU16 + 4096 + wv * 512]);
  };

  s16x8 Af[4][2], Bf[4][2];
  f32x4 acc[8][4];
  const f32x4 z4 = {0.f, 0.f, 0.f, 0.f};
#pragma unroll
  for (int i = 0; i < 8; ++i)
#pragma unroll
    for (int j = 0; j < 4; ++j) acc[i][j] = z4;

  const int xorw = (lm & 4) << 2;   // swizzle XOR in u16 units (32B)

#define DSA(s, mh)                                                          \
  _Pragma("unroll") for (int f = 0; f < 4; ++f)                             \
  _Pragma("unroll") for (int ks = 0; ks < 2; ++ks)                          \
    Af[f][ks] = *(const s16x8*)&lds[RA(s, wm) +                             \
      (((((mh) * 4 + f) * 16 + lm) * 64 + ks * 32 + lq * 8) ^ xorw)];

#define DSB(s)                                                              \
  _Pragma("unroll") for (int f = 0; f < 4; ++f)                             \
  _Pragma("unroll") for (int ks = 0; ks < 2; ++ks)                          \
    Bf[f][ks] = *(const s16x8*)&lds[RB(s, wn >> 1) +                        \
      ((((wn & 1) * 64 + f * 16 + lm) * 64 + ks * 32 + lq * 8) ^ xorw)];

#define QUAD(mh, nh)                                                        \
  do {                                                                      \
    __builtin_amdgcn_s_setprio(1);                                          \
    _Pragma("unroll") for (int f = 0; f < 4; ++f)                           \
    _Pragma("unroll") for (int n = 0; n < 2; ++n)                           \
    _Pragma("unroll") for (int ks = 0; ks < 2; ++ks)                        \
      acc[(mh) * 4 + f][(nh) * 2 + n] =                                     \
          __builtin_amdgcn_mfma_f32_16x16x32_bf16(                          \
              Af[f][ks], Bf[(nh) * 2 + n][ks],                              \
              acc[(mh) * 4 + f][(nh) * 2 + n], 0, 0, 0);                    \
    __builtin_amdgcn_s_setprio(0);                                          \
  } while (0)

  // ---- prologue: 7 halves (t0 full + t1 B0,B1,A0); t1A1 comes at p0 ----
  stageH(A, bm, lda, 0, RA(0, 0));
  stageH(A, bm + 128, lda, 0, RA(0, 1));
  stageH(Bt, bn, ldb, 0, RB(0, 0));
  stageH(Bt, bn + 128, ldb, 0, RB(0, 1));
  stageH(Bt, bn, ldb, 1, RB(1, 0));
  stageH(Bt, bn + 128, ldb, 1, RB(1, 1));
  stageH(A, bm, lda, 1, RA(1, 0));
  VMCNT6();        // first 4 halves (tile 0) landed
  SBAR();

#pragma unroll 1
  for (int t = 0; t < NT2; ++t) {
    const int T2 = 2 * t + 2, T3 = 2 * t + 3;
    // -------- tile 2t from slot 0 --------
    // p0
    DSA(0, 0); DSB(0);
    stageH(A, bm + 128, lda, 2 * t + 1, RA(1, 1));   // s1A1 of tile 2t+1
    SBAR();
    QUAD(0, 0);
    SBAR();
    // p1
    if (T2 < NT) stageH(Bt, bn, ldb, T2, RB(0, 0));
    SBAR();
    QUAD(0, 1);
    SBAR();
    // p2
    DSA(0, 1);
    if (T2 < NT) stageH(Bt, bn + 128, ldb, T2, RB(0, 1));
    SBAR();
    QUAD(1, 0);
    SBAR();
    // p3
    if (T2 < NT) stageH(A, bm, lda, T2, RA(0, 0));
    SBAR();
    QUAD(1, 1);
    VMCNT6();      // slot1 (tile 2t+1) fully landed before p4 reads
    SBAR();
    // -------- tile 2t+1 from slot 1 --------
    // p4
    DSA(1, 0); DSB(1);
    if (T2 < NT) stageH(A, bm + 128, lda, T2, RA(0, 1));
    SBAR();
    QUAD(0, 0);
    SBAR();
    // p5
    if (T3 < NT) stageH(Bt, bn, ldb, T3, RB(1, 0));
    SBAR();
    QUAD(0, 1);
    SBAR();
    // p6
    DSA(1, 1);
    if (T3 < NT) stageH(Bt, bn + 128, ldb, T3, RB(1, 1));
    SBAR();
    QUAD(1, 0);
    SBAR();
    // p7
    if (T3 < NT) stageH(A, bm, lda, T3, RA(1, 0));
    SBAR();
    QUAD(1, 1);
    VMCNT6();      // slot0 (tile 2t+2) fully landed before next p0 reads
    SBAR();
  }

  // epilogue: D col = lm, row = lq*4 + r within each 16x16 fragment
#pragma unroll
  for (int f = 0; f < 8; ++f) {
#pragma unroll
    for (int n = 0; n < 4; ++n) {
#pragma unroll
      for (int r = 0; r < 4; ++r) {
        const int row = bm + wm * 128 + f * 16 + lq * 4 + r;
        const int col = bn + wn * 64 + n * 16 + lm;
        if (col < Ncols) {
          if (OUT_BF16)
            ((u16*)C)[(size_t)row * ldc + col] = f2bf(acc[f][n][r]);
          else
            ((float*)C)[(size_t)row * ldc + col] = acc[f][n][r];
        }
      }
    }
  }
#undef DSA
#undef DSB
#undef QUAD
}

// ---------------- conv + p_w + phase features (reads z bf16) --------------
__global__ __launch_bounds__(256) void conv_feat_kernel(
    const u16* __restrict__ z, const float* __restrict__ kern,
    const float* __restrict__ theta, const float* __restrict__ decay,
    const float* __restrict__ anchor, const float* __restrict__ sscale,
    float* __restrict__ merged) {
  __shared__ u16 zw[11 * ZLD];    // 45760 B
  __shared__ float spw[8][32];
  const int tid = threadIdx.x;
  const int r0 = blockIdx.x * 8;
  const bool first = ((r0 & (LL - 1)) == 0);

  for (int idx = tid; idx < 11 * (ZLD / 8); idx += 256) {
    const int i = idx / (ZLD / 8);
    const int c8 = idx - i * (ZLD / 8);
    s16x8 v = {0, 0, 0, 0, 0, 0, 0, 0};
    if (!(first && i < 3))
      v = *(const s16x8*)(z + (size_t)(r0 - 3 + i) * ZLD + c8 * 8);
    *(s16x8*)&zw[i * ZLD + c8 * 8] = v;
  }
  __syncthreads();

  {  // scores -> p_w (8 rows x 32 heads = 256 threads)
    const int rr = tid >> 5, k = tid & 31;
    float v = 0.f;
#pragma unroll
    for (int w = 0; w < CKK; ++w)
      v = fmaf(bf2f(zw[(rr + w) * ZLD + 2048 + k]), kern[w * ZC + 2048 + k], v);
    const int l = (r0 + rr) & (LL - 1);
    const float slope = (k < KK - AA) ? decay[k] : anchor[k - (KK - AA)];
    const float sp = log1pf(__expf(slope));
    const float lw = (k < KK - AA) ? (-sp * (float)(LL - 1 - l)) : (-sp * (float)l);
    const float p = __expf(sscale[k] * v + lw);
    spw[rr][k] = p;
    merged[(size_t)(r0 + rr) * ZC + k] = p;
  }
  __syncthreads();

#pragma unroll 1
  for (int it = 0; it < 4; ++it) {
    const int c = it * 256 + tid;   // 0..1023
    const float kw0 = kern[0 * ZC + c], kw1 = kern[1 * ZC + c];
    const float kw2 = kern[2 * ZC + c], kw3 = kern[3 * ZC + c];
    const float th = theta[c];
    float zv[11];
#pragma unroll
    for (int i = 0; i < 11; ++i) zv[i] = bf2f(zw[i * ZLD + c]);
#pragma unroll
    for (int rr = 0; rr < 8; ++rr) {
      float v = zv[rr] * kw0;
      v = fmaf(zv[rr + 1], kw1, v);
      v = fmaf(zv[rr + 2], kw2, v);
      v = fmaf(zv[rr + 3], kw3, v);
      const float phi = v * th;
      float sv, cv;
      __sincosf(phi, &sv, &cv);
      const float p = spw[rr][c >> 5];
      float* mrow = merged + (size_t)(r0 + rr) * ZC;
      mrow[KK + c] = p * cv;
      mrow[KK + FLATC + c] = p * sv;
    }
  }
}

// ---------------- blocked scan over L ----------------
__global__ __launch_bounds__(256) void scan_partial_kernel(
    const float* __restrict__ merged, float* __restrict__ part) {
  const int c = blockIdx.x * 256 + threadIdx.x;
  const int chunk = blockIdx.y, b = blockIdx.z;
  if (c >= ZC) return;
  size_t base = ((size_t)b * LL + (size_t)chunk * CH) * ZC + c;
  float s = 0.f;
#pragma unroll 8
  for (int i = 0; i < CH; ++i) s += merged[base + (size_t)i * ZC];
  part[((size_t)b * NCH + chunk) * ZC + c] = s;
}

__global__ __launch_bounds__(256) void scan_offsets_kernel(float* __restrict__ part) {
  const int c = blockIdx.x * 256 + threadIdx.x;
  const int b = blockIdx.z;
  if (c >= ZC) return;
  float run = 0.f;
#pragma unroll
  for (int i = 0; i < NCH; ++i) {
    const size_t idx = ((size_t)b * NCH + i) * ZC + c;
    const float t = part[idx];
    part[idx] = run;
    run += t;
  }
}

__global__ __launch_bounds__(256) void scan_apply_kernel(
    float* __restrict__ merged, const float* __restrict__ part) {
  const int c = blockIdx.x * 256 + threadIdx.x;
  const int chunk = blockIdx.y, b = blockIdx.z;
  if (c >= ZC) return;
  float s = part[((size_t)b * NCH + chunk) * ZC + c];
  size_t base = ((size_t)b * LL + (size_t)chunk * CH) * ZC + c;
#pragma unroll 4
  for (int i = 0; i < CH; ++i) {
    const size_t idx = base + (size_t)i * ZC;
    s += merged[idx];
    merged[idx] = s;
  }
}

// ---------------- fold norm_scale into head weights (bf16) ----------------
__global__ __launch_bounds__(256) void wprime_kernel(
    const float* __restrict__ W_re, const float* __restrict__ W_im,
    const float* __restrict__ ns, u16* __restrict__ wp) {
  const int i = blockIdx.x * 256 + threadIdx.x;   // 0..2047
  if (i < 1024) wp[i] = f2bf(ns[i >> 5] * W_re[i]);
  else {
    const int j = i - 1024;
    wp[i] = f2bf(ns[32 + (j >> 5)] * W_im[j]);
  }
}

// ---------------- norm_head via MFMA ----------------
// Block = 8 bl rows (4 waves x 2 rows). Per (bl,k) row: scale from raw row
// sums, y = [re;im]*scale @ [Wre';Wim'] via 16x16x32 bf16 MFMA, g = y*gate
// written bf16 in-place into merged row head (den read before any write).
__global__ __launch_bounds__(256) void norm_head_mfma(
    float* merged, const u16* __restrict__ z, const float* __restrict__ kern,
    const u16* __restrict__ wp) {
  __shared__ u16 zw[11 * GLD];       // skewed gate-z tile
  __shared__ float skern[4 * KLD];   // skewed gate conv weights
  const int tid = threadIdx.x;
  const int r0 = blockIdx.x * 8;
  const bool first = ((r0 & (LL - 1)) == 0);
  const int lane = tid & 63, wv = tid >> 6;
  const int lm = lane & 15, lq = lane >> 4;

  // stage z gate cols (1024..2047), rows r0-3 .. r0+7, with skew
  for (int idx = tid; idx < 11 * 128; idx += 256) {
    const int i = idx >> 7, c8 = idx & 127;
    s16x8 v = {0, 0, 0, 0, 0, 0, 0, 0};
    if (!(first && i < 3))
      v = *(const s16x8*)(z + (size_t)(r0 - 3 + i) * ZLD + 1024 + c8 * 8);
    *(s16x8*)&zw[i * GLD + c8 * 8 + (c8 >> 4) * 16] = v;
  }
  // stage gate conv weights (f32) with skew
  for (int idx = tid; idx < 4 * 256; idx += 256) {
    const int w = idx >> 8, c4 = idx & 255;
    float4 v = *(const float4*)(kern + w * ZC + 1024 + c4 * 4);
    *(float4*)&skern[w * KLD + c4 * 4 + (c4 >> 5) * 8] = v;
  }

  // B fragments (same for all rows): lane(lm,lq) holds W'[lq*8+j][nt*16+lm]
  s16x8 bre[2], bim[2];
#pragma unroll
  for (int nt = 0; nt < 2; ++nt)
#pragma unroll
    for (int jj = 0; jj < 8; ++jj) {
      bre[nt][jj] = (short)wp[(lq * 8 + jj) * 32 + nt * 16 + lm];
      bim[nt][jj] = (short)wp[1024 + (lq * 8 + jj) * 32 + nt * 16 + lm];
    }
  __syncthreads();

  const f32x4 z4 = {0.f, 0.f, 0.f, 0.f};
#pragma unroll 1
  for (int rr2 = 0; rr2 < 2; ++rr2) {
    const int rr = wv * 2 + rr2;          // 0..7 within block
    const int bl = r0 + rr;
    float* row = merged + (size_t)bl * ZC;
    // den for BOTH k-halves, before any write to this row
    const float den0 = row[lm], den1 = row[16 + lm];

#pragma unroll
    for (int khalf = 0; khalf < 2; ++khalf) {
      // A loads: re/im for (bl, k = khalf*16+lm), hp = lq*8..lq*8+7
      const float* rp = row + KK + (khalf * 16 + lm) * 32 + lq * 8;
      float4 ra = *(const float4*)rp;
      float4 rb = *(const float4*)(rp + 4);
      float4 ia = *(const float4*)(rp + FLATC);
      float4 ib = *(const float4*)(rp + FLATC + 4);

      float ssq = ra.x * ra.x + ra.y * ra.y + ra.z * ra.z + ra.w * ra.w +
                  rb.x * rb.x + rb.y * rb.y + rb.z * rb.z + rb.w * rb.w +
                  ia.x * ia.x + ia.y * ia.y + ia.z * ia.z + ia.w * ia.w +
                  ib.x * ib.x + ib.y * ib.y + ib.z * ib.z + ib.w * ib.w;
      ssq += __shfl_xor(ssq, 16);
      ssq += __shfl_xor(ssq, 32);
      const float den = khalf ? den1 : den0;
      const float inv = 1.0f / fmaxf(den, 1e-4f);
      const float scale = inv * rsqrtf(ssq * inv * inv * (1.0f / 64.0f) + 1e-5f);

      s16x8 afr, afi;
      afr[0] = (short)f2bf(ra.x * scale); afr[1] = (short)f2bf(ra.y * scale);
      afr[2] = (short)f2bf(ra.z * scale); afr[3] = (short)f2bf(ra.w * scale);
      afr[4] = (short)f2bf(rb.x * scale); afr[5] = (short)f2bf(rb.y * scale);
      afr[6] = (short)f2bf(rb.z * scale); afr[7] = (short)f2bf(rb.w * scale);
      afi[0] = (short)f2bf(ia.x * scale); afi[1] = (short)f2bf(ia.y * scale);
      afi[2] = (short)f2bf(ia.z * scale); afi[3] = (short)f2bf(ia.w * scale);
      afi[4] = (short)f2bf(ib.x * scale); afi[5] = (short)f2bf(ib.y * scale);
      afi[6] = (short)f2bf(ib.z * scale); afi[7] = (short)f2bf(ib.w * scale);

      f32x4 acc[2];
#pragma unroll
      for (int nt = 0; nt < 2; ++nt) {
        acc[nt] = __builtin_amdgcn_mfma_f32_16x16x32_bf16(afr, bre[nt], z4, 0, 0, 0);
        acc[nt] = __builtin_amdgcn_mfma_f32_16x16x32_bf16(afi, bim[nt], acc[nt], 0, 0, 0);
      }

      // epilogue: D row = lq*4+r (k offset), col = lm (h offset)
      u16* grow = (u16*)row;
#pragma unroll
      for (int nt = 0; nt < 2; ++nt) {
#pragma unroll
        for (int r = 0; r < 4; ++r) {
          const int k = khalf * 16 + lq * 4 + r;
          const int o = k * 32 + nt * 16 + lm;
          const int sk = o + (o >> 7) * 8;    // skern skew
          const int sz = o + (o >> 7) * 16;   // zw skew
          float gv = bf2f(zw[(rr + 0) * GLD + sz]) * skern[0 * KLD + sk];
          gv = fmaf(bf2f(zw[(rr + 1) * GLD + sz]), skern[1 * KLD + sk], gv);
          gv = fmaf(bf2f(zw[(rr + 2) * GLD + sz]), skern[2 * KLD + sk], gv);
          gv = fmaf(bf2f(zw[(rr + 3) * GLD + sz]), skern[3 * KLD + sk], gv);
          const float sil = gv * (1.0f / (1.0f + __expf(-gv)));
          grow[o] = f2bf(acc[nt][r] * sil);
        }
      }
    }
  }
}

// ---------------- launch ----------------
extern "C" void kernel_launch(void* const* d_in, const int* in_sizes, int n_in,
                              void* d_out, int out_size, void* d_ws, size_t ws_size,
                              hipStream_t stream) {
  const float* x      = (const float*)d_in[0];
  const float* W_in   = (const float*)d_in[1];
  const float* kern   = (const float*)d_in[2];
  const float* theta  = (const float*)d_in[3];
  const float* decay  = (const float*)d_in[4];
  const float* anchor = (const float*)d_in[5];
  const float* sscale = (const float*)d_in[6];
  const float* W_re   = (const float*)d_in[7];
  const float* W_im   = (const float*)d_in[8];
  const float* nscale = (const float*)d_in[9];
  const float* W_out  = (const float*)d_in[10];
  float* out = (float*)d_out;

  // workspace layout (~199.8 MiB + 4 KB):
  char* w = (char*)d_ws;
  float* merged = (float*)w;
  u16* xbf = (u16*)w;                                  // alias: dead once gemm1 done
  u16* zbf = (u16*)(w + (size_t)BL * ZC * 4);
  u16* wobt = zbf;                                     // alias: written after norm_head
  u16* wbt = (u16*)(w + (size_t)BL * ZC * 4 + (size_t)BL * ZLD * 2);
  float* part = (float*)((char*)wbt + (size_t)NPAD * DD * 2);
  u16* wp = (u16*)(part + (size_t)BB * NCH * ZC);      // 2048 u16

  // 1) casts / transposes / weight fold
  cast_bf16_kernel<<<dim3(BL * DD / 8 / 256), 256, 0, stream>>>(x, xbf, BL * DD);
  transpose_cast_kernel<<<dim3(32, 68), 256, 0, stream>>>(W_in, wbt, DD, ZC, NPAD);
  wprime_kernel<<<dim3(8), 256, 0, stream>>>(W_re, W_im, nscale, wp);

  // 2) GEMM1: z = x @ W_in  (bf16 MFMA, bf16 out). grid.x = row tiles
  // (64 % 8 == 0 -> row stripe pinned to one XCD's L2 across col tiles).
  // Col tile 8 stages B rows 2176..2303: reads spill past wbt into the
  // part region (in-workspace); any NaNs land in cols >= 2176, all masked
  // by the col < Ncols(2080) write guard.
  gemm256_8ph<1><<<dim3(BL / 256, 9), 512, 0, stream>>>(
      xbf, wbt, zbf, DD, DD, ZLD, DD, ZC);

  // 3) conv + p_w + features -> merged
  conv_feat_kernel<<<dim3(BL / 8), 256, 0, stream>>>(zbf, kern, theta, decay,
                                                     anchor, sscale, merged);

  // 4) blocked inclusive scan over L (in-place on merged)
  {
    dim3 grid((ZC + 255) / 256, NCH, BB);
    scan_partial_kernel<<<grid, 256, 0, stream>>>(merged, part);
    dim3 grid2((ZC + 255) / 256, 1, BB);
    scan_offsets_kernel<<<grid2, 256, 0, stream>>>(part);
    scan_apply_kernel<<<grid, 256, 0, stream>>>(merged, part);
  }

  // 5) normalize + RMS + head matmuls (MFMA) + gate -> g (bf16, in-place)
  norm_head_mfma<<<dim3(BL / 8), 256, 0, stream>>>(merged, zbf, kern, wp);

  // 6) W_out^T (into dead z region), then GEMM2: out = g @ W_out (f32 out)
  transpose_cast_kernel<<<dim3(32, 32), 256, 0, stream>>>(W_out, wobt, DI, DD, DD);
  gemm256_8ph<0><<<dim3(BL / 256, DD / 256), 512, 0, stream>>>(
      (const u16*)merged, wobt, out, 2 * ZC, DI, DD, DI, DD);
}

// Round 3
// 372.230 us; speedup vs baseline: 1.3979x; 1.1959x over previous
//
#include <hip/hip_runtime.h>
#include <hip/hip_bf16.h>
#include <math.h>

// ---------------- static problem config ----------------
#define BB 4
#define LL 4096
#define DD 1024
#define KK 32
#define HH 32
#define AA 4
#define CKK 4
#define DI 1024
#define ZC 2080            // 2*DI + KK
#define FLATC 1024         // K*H
#define BL (BB * LL)       // 16384
#define ZLD 2080           // z row stride (bf16)
#define NPAD 2176          // W_in^T padded rows (17*128)

// scan config: chunk == conv block == 32 rows
#define CCH 32
#define NCHK (LL / CCH)    // 128 chunks per b

// norm_head LDS strides (skewed to break lq-stride-128 bank conflicts)
#define GLD 1136           // zw row stride in u16 : col = o + (o>>7)*16
#define KLD 1080           // skern row stride in f32: col = o + (o>>7)*8

typedef unsigned short u16;
typedef __attribute__((ext_vector_type(8))) short s16x8;
typedef __attribute__((ext_vector_type(4))) float f32x4;

__device__ __forceinline__ u16 f2bf(float f) {
  union { float f; unsigned int u; } v; v.f = f;
  unsigned int r = (v.u + 0x7FFFu + ((v.u >> 16) & 1u)) >> 16;
  return (u16)r;
}
__device__ __forceinline__ float bf2f(u16 u) {
  union { unsigned int i; float f; } x; x.i = ((unsigned int)u) << 16; return x.f;
}
__device__ __forceinline__ void gl_lds16(const void* g, void* l) {
  __builtin_amdgcn_global_load_lds(
      (const __attribute__((address_space(1))) unsigned int*)g,
      (__attribute__((address_space(3))) unsigned int*)l, 16, 0, 0);
}

// ---------------- cast f32 -> bf16 (x) ----------------
__global__ __launch_bounds__(256) void cast_bf16_kernel(
    const float* __restrict__ src, u16* __restrict__ dst, int n) {
  const int i = (blockIdx.x * 256 + threadIdx.x) * 8;
  if (i >= n) return;
  float4 a = *(const float4*)(src + i);
  float4 b = *(const float4*)(src + i + 4);
  s16x8 v;
  v[0] = (short)f2bf(a.x); v[1] = (short)f2bf(a.y);
  v[2] = (short)f2bf(a.z); v[3] = (short)f2bf(a.w);
  v[4] = (short)f2bf(b.x); v[5] = (short)f2bf(b.y);
  v[6] = (short)f2bf(b.z); v[7] = (short)f2bf(b.w);
  *(s16x8*)(dst + i) = v;
}

// ---------------- transpose + cast: src[R][C] f32 -> dst[Cpad][R] bf16 ----
__global__ __launch_bounds__(256) void transpose_cast_kernel(
    const float* __restrict__ src, u16* __restrict__ dst,
    int R, int C, int Cpad) {
  __shared__ float t[32][33];
  const int tid = threadIdx.x;
  const int r0 = blockIdx.x * 32, c0 = blockIdx.y * 32;
  const int lr = tid >> 5, lc = tid & 31;
#pragma unroll
  for (int i = 0; i < 4; ++i) {
    const int r = r0 + i * 8 + lr, c = c0 + lc;
    float v = 0.f;
    if (r < R && c < C) v = src[(size_t)r * C + c];
    t[lc][i * 8 + lr] = v;
  }
  __syncthreads();
#pragma unroll
  for (int i = 0; i < 4; ++i) {
    const int dr = c0 + i * 8 + lr;   // row in dst = col in src
    const int dc = r0 + lc;           // col in dst = row in src
    if (dr < Cpad && dc < R) dst[(size_t)dr * R + dc] = f2bf(t[i * 8 + lr][lc]);
  }
}

// ---------------- 256x256 8-phase bf16 MFMA GEMM (T1+T2+T3+T4+T5) --------
// C[M,N] = A[M,K] * Bt[N,K]^T.  512 threads = 8 waves (2M x 4N), per-wave
// output 128x64 (8x4 fragments of 16x16), BK=64, NT = K/64 tiles (even).
//
// LDS 128KB: 8 half-regions of 16KB (128 rows x 64 cols bf16, row-major).
// 3-bit XOR swizzle: elem_col ^= (row&7)<<3 (bytes: col ^= (row&7)<<4).
// Per ds_read_b128 the wave's 64 lanes then cover all 8 16B slots with 8
// lanes each = 2 lanes/bank/cycle = conflict-free (G4, m136).
// global_load_lds writes LINEAR dest (dest row&7 == lane>>3), so the
// swizzle is applied by pre-swizzling the GLOBAL source column
// (8*((lane&7)^(lane>>3)) elems); reads apply the same XOR (rule #21).
//
// Stage stream (1 half/phase): p0: s1A1(T2t+1), p1: s0B0(T2t+2),
// p2: s0B1, p3: s0A0, p4: s0A1, p5: s1B0(T2t+3), p6: s1B1, p7: s1A0.
// Gates: s_waitcnt vmcnt(6) at end of p3 and p7 ONLY (3 halves = 6 loads
// allowed in flight).  Raw s_barrier + compiler fence (no __syncthreads,
// so no vmcnt(0) drain) keeps prefetch loads in flight across barriers.
#define FENCE() asm volatile("" ::: "memory")
#define SBAR() do { FENCE(); __builtin_amdgcn_s_barrier(); FENCE(); } while (0)
#define VMCNT6() asm volatile("s_waitcnt vmcnt(6)" ::: "memory")

// region u16 offsets: A(s,h) = (s*2+h)*8192 ; B(s,h) = 32768 + (s*2+h)*8192
#define RA(s, h) (((s) * 2 + (h)) * 8192)
#define RB(s, h) (32768 + ((s) * 2 + (h)) * 8192)

template <int OUT_BF16>
__global__ __launch_bounds__(512, 2) void gemm256_8ph(
    const u16* __restrict__ A, const u16* __restrict__ Bt, void* __restrict__ C,
    int lda, int ldb, int ldc, int Kd, int Ncols) {
  __shared__ u16 lds[65536];   // 128 KiB
  const int tid = threadIdx.x;
  const int lane = tid & 63, wv = tid >> 6;
  const int wm = wv >> 2, wn = wv & 3;       // 2M x 4N wave grid
  const int lm = lane & 15, lq = lane >> 4;
  const int bm = blockIdx.x * 256, bn = blockIdx.y * 256;
  const int NT = Kd >> 6;                    // K tiles (even)
  const int NT2 = NT >> 1;

  // staging: per wave per call, 2x global_load_lds(16B) cover one 16KB
  // half-region (128 rows x 128B). LDS dest linear: row = wv*8+(lane>>3),
  // colbyte = (lane&7)*16. Source col pre-swizzled with the 3-bit XOR:
  const int rofs = wv * 8 + (lane >> 3);                 // region row
  const int cel = ((lane & 7) ^ (lane >> 3)) * 8;        // col elems, swz

  auto stageH = [&](const u16* __restrict__ G, int rowBase, int ld, int kt,
                    int regU16) {
    const u16* g0 = G + (size_t)(rowBase + rofs) * ld + (kt << 6) + cel;
    gl_lds16(g0, &lds[regU16 + wv * 512]);
    const u16* g1 = G + (size_t)(rowBase + 64 + rofs) * ld + (kt << 6) + cel;
    gl_lds16(g1, &lds[regU16 + 4096 + wv * 512]);
  };

  s16x8 Af[4][2], Bf[4][2];
  f32x4 acc[8][4];
  const f32x4 z4 = {0.f, 0.f, 0.f, 0.f};
#pragma unroll
  for (int i = 0; i < 8; ++i)
#pragma unroll
    for (int j = 0; j < 4; ++j) acc[i][j] = z4;

  const int xorw = (lm & 7) << 3;   // read-side swizzle XOR in u16 units

#define DSA(s, mh)                                                          \
  _Pragma("unroll") for (int f = 0; f < 4; ++f)                             \
  _Pragma("unroll") for (int ks = 0; ks < 2; ++ks)                          \
    Af[f][ks] = *(const s16x8*)&lds[RA(s, wm) +                             \
      (((((mh) * 4 + f) * 16 + lm) * 64 + ((ks * 32 + lq * 8) ^ xorw)))];

#define DSB(s)                                                              \
  _Pragma("unroll") for (int f = 0; f < 4; ++f)                             \
  _Pragma("unroll") for (int ks = 0; ks < 2; ++ks)                          \
    Bf[f][ks] = *(const s16x8*)&lds[RB(s, wn >> 1) +                        \
      ((((wn & 1) * 64 + f * 16 + lm) * 64 + ((ks * 32 + lq * 8) ^ xorw)))];

#define QUAD(mh, nh)                                                        \
  do {                                                                      \
    __builtin_amdgcn_s_setprio(1);                                          \
    _Pragma("unroll") for (int f = 0; f < 4; ++f)                           \
    _Pragma("unroll") for (int n = 0; n < 2; ++n)                           \
    _Pragma("unroll") for (int ks = 0; ks < 2; ++ks)                        \
      acc[(mh) * 4 + f][(nh) * 2 + n] =                                     \
          __builtin_amdgcn_mfma_f32_16x16x32_bf16(                          \
              Af[f][ks], Bf[(nh) * 2 + n][ks],                              \
              acc[(mh) * 4 + f][(nh) * 2 + n], 0, 0, 0);                    \
    __builtin_amdgcn_s_setprio(0);                                          \
  } while (0)

  // ---- prologue: 7 halves (t0 full + t1 B0,B1,A0); t1A1 comes at p0 ----
  stageH(A, bm, lda, 0, RA(0, 0));
  stageH(A, bm + 128, lda, 0, RA(0, 1));
  stageH(Bt, bn, ldb, 0, RB(0, 0));
  stageH(Bt, bn + 128, ldb, 0, RB(0, 1));
  stageH(Bt, bn, ldb, 1, RB(1, 0));
  stageH(Bt, bn + 128, ldb, 1, RB(1, 1));
  stageH(A, bm, lda, 1, RA(1, 0));
  VMCNT6();        // first 4 halves (tile 0) landed
  SBAR();

#pragma unroll 1
  for (int t = 0; t < NT2; ++t) {
    const int T2 = 2 * t + 2, T3 = 2 * t + 3;
    // -------- tile 2t from slot 0 --------
    // p0
    DSA(0, 0); DSB(0);
    stageH(A, bm + 128, lda, 2 * t + 1, RA(1, 1));   // s1A1 of tile 2t+1
    SBAR();
    QUAD(0, 0);
    SBAR();
    // p1
    if (T2 < NT) stageH(Bt, bn, ldb, T2, RB(0, 0));
    SBAR();
    QUAD(0, 1);
    SBAR();
    // p2
    DSA(0, 1);
    if (T2 < NT) stageH(Bt, bn + 128, ldb, T2, RB(0, 1));
    SBAR();
    QUAD(1, 0);
    SBAR();
    // p3
    if (T2 < NT) stageH(A, bm, lda, T2, RA(0, 0));
    SBAR();
    QUAD(1, 1);
    VMCNT6();      // slot1 (tile 2t+1) fully landed before p4 reads
    SBAR();
    // -------- tile 2t+1 from slot 1 --------
    // p4
    DSA(1, 0); DSB(1);
    if (T2 < NT) stageH(A, bm + 128, lda, T2, RA(0, 1));
    SBAR();
    QUAD(0, 0);
    SBAR();
    // p5
    if (T3 < NT) stageH(Bt, bn, ldb, T3, RB(1, 0));
    SBAR();
    QUAD(0, 1);
    SBAR();
    // p6
    DSA(1, 1);
    if (T3 < NT) stageH(Bt, bn + 128, ldb, T3, RB(1, 1));
    SBAR();
    QUAD(1, 0);
    SBAR();
    // p7
    if (T3 < NT) stageH(A, bm, lda, T3, RA(1, 0));
    SBAR();
    QUAD(1, 1);
    VMCNT6();      // slot0 (tile 2t+2) fully landed before next p0 reads
    SBAR();
  }

  // epilogue: D col = lm, row = lq*4 + r within each 16x16 fragment
#pragma unroll
  for (int f = 0; f < 8; ++f) {
#pragma unroll
    for (int n = 0; n < 4; ++n) {
#pragma unroll
      for (int r = 0; r < 4; ++r) {
        const int row = bm + wm * 128 + f * 16 + lq * 4 + r;
        const int col = bn + wn * 64 + n * 16 + lm;
        if (col < Ncols) {
          if (OUT_BF16)
            ((u16*)C)[(size_t)row * ldc + col] = f2bf(acc[f][n][r]);
          else
            ((float*)C)[(size_t)row * ldc + col] = acc[f][n][r];
        }
      }
    }
  }
#undef DSA
#undef DSB
#undef QUAD
}

// ---------------- conv + p_w + features + chunk-local cumsum --------------
// One block = one 32-row chunk. Features are computed with a rolling
// 4-deep z history in registers and accumulated into a chunk-local
// inclusive cumsum (registers, while values are live); the chunk total
// goes to part[chunk]. This deletes the scan_partial (136 MB read) and
// scan_apply (272 MB r+w) passes entirely.
__global__ __launch_bounds__(256) void conv_feat_scan(
    const u16* __restrict__ z, const float* __restrict__ kern,
    const float* __restrict__ theta, const float* __restrict__ decay,
    const float* __restrict__ anchor, const float* __restrict__ sscale,
    float* __restrict__ merged, float* __restrict__ part) {
  __shared__ float pbuf[CCH][KK];   // raw p_w per (row, head)
  const int tid = threadIdx.x;
  const int r0 = blockIdx.x * CCH;           // global row base
  const bool first = ((r0 & (LL - 1)) == 0);
  const int chunk = blockIdx.x;              // global chunk id

  // phase A: p_w for 32 rows x 32 heads (4 items/thread)
#pragma unroll
  for (int q = 0; q < 4; ++q) {
    const int item = q * 256 + tid;
    const int row = item >> 5, k = item & 31;
    float v = 0.f;
#pragma unroll
    for (int w = 0; w < CKK; ++w) {
      const int g = row + w;                 // offset from r0-3
      float zv = 0.f;
      if (!(first && g < 3))
        zv = bf2f(z[(size_t)(r0 - 3 + g) * ZLD + 2048 + k]);
      v = fmaf(zv, kern[w * ZC + 2048 + k], v);
    }
    const int l = (r0 + row) & (LL - 1);
    const float slope = (k < KK - AA) ? decay[k] : anchor[k - (KK - AA)];
    const float sp = log1pf(__expf(slope));
    const float lw = (k < KK - AA) ? (-sp * (float)(LL - 1 - l)) : (-sp * (float)l);
    pbuf[row][k] = __expf(sscale[k] * v + lw);
  }
  __syncthreads();

  // phase B: den chunk-local cumsum (32 threads; LDS reads conflict-free)
  if (tid < KK) {
    float run = 0.f;
#pragma unroll
    for (int row = 0; row < CCH; ++row) {
      run += pbuf[row][tid];
      merged[(size_t)(r0 + row) * ZC + tid] = run;
    }
    part[(size_t)chunk * ZC + tid] = run;
  }

  // phase C: features + chunk-local cumsum (reads pbuf raw, no extra sync
  // needed: phase B wrote only global memory)
#pragma unroll 1
  for (int it = 0; it < 4; ++it) {
    const int c = it * 256 + tid;            // 0..1023
    const float kw0 = kern[0 * ZC + c], kw1 = kern[1 * ZC + c];
    const float kw2 = kern[2 * ZC + c], kw3 = kern[3 * ZC + c];
    const float th = theta[c];
    const int head = c >> 5;
    float h0 = 0.f, h1 = 0.f, h2 = 0.f;      // rolling z history
    if (!first) {
      h0 = bf2f(z[(size_t)(r0 - 3) * ZLD + c]);
      h1 = bf2f(z[(size_t)(r0 - 2) * ZLD + c]);
      h2 = bf2f(z[(size_t)(r0 - 1) * ZLD + c]);
    }
    float sre = 0.f, sim = 0.f;
#pragma unroll 4
    for (int row = 0; row < CCH; ++row) {
      const float h3 = bf2f(z[(size_t)(r0 + row) * ZLD + c]);
      float v = h0 * kw0;
      v = fmaf(h1, kw1, v);
      v = fmaf(h2, kw2, v);
      v = fmaf(h3, kw3, v);
      h0 = h1; h1 = h2; h2 = h3;
      const float phi = v * th;
      float sv, cv;
      __sincosf(phi, &sv, &cv);
      const float p = pbuf[row][head];
      sre = fmaf(p, cv, sre);
      sim = fmaf(p, sv, sim);
      float* mrow = merged + (size_t)(r0 + row) * ZC;
      mrow[KK + c] = sre;
      mrow[KK + FLATC + c] = sim;
    }
    part[(size_t)chunk * ZC + KK + c] = sre;
    part[(size_t)chunk * ZC + KK + FLATC + c] = sim;
  }
}

// ---------------- exclusive scan of chunk totals (128 chunks per b) -------
__global__ __launch_bounds__(256) void scan_offsets_kernel(float* __restrict__ part) {
  const int c = blockIdx.x * 256 + threadIdx.x;
  const int b = blockIdx.z;
  if (c >= ZC) return;
  float run = 0.f;
#pragma unroll 8
  for (int i = 0; i < NCHK; ++i) {
    const size_t idx = ((size_t)b * NCHK + i) * ZC + c;
    const float t = part[idx];
    part[idx] = run;
    run += t;
  }
}

// ---------------- fold norm_scale into head weights (bf16) ----------------
__global__ __launch_bounds__(256) void wprime_kernel(
    const float* __restrict__ W_re, const float* __restrict__ W_im,
    const float* __restrict__ ns, u16* __restrict__ wp) {
  const int i = blockIdx.x * 256 + threadIdx.x;   // 0..2047
  if (i < 1024) wp[i] = f2bf(ns[i >> 5] * W_re[i]);
  else {
    const int j = i - 1024;
    wp[i] = f2bf(ns[32 + (j >> 5)] * W_im[j]);
  }
}

// ---------------- norm_head via MFMA ----------------
// Block = 8 bl rows (4 waves x 2 rows). merged holds CHUNK-LOCAL cumsum;
// the global prefix is chunk-local + part[chunk] (exclusive offsets),
// added at load time (den and re/im). Per (bl,k) row: scale from raw row
// sums, y = [re;im]*scale @ [Wre';Wim'] via 16x16x32 bf16 MFMA, g = y*gate
// written bf16 in-place into merged row head (den read before any write).
__global__ __launch_bounds__(256) void norm_head_mfma(
    float* merged, const u16* __restrict__ z, const float* __restrict__ kern,
    const u16* __restrict__ wp, const float* __restrict__ part) {
  __shared__ u16 zw[11 * GLD];       // skewed gate-z tile
  __shared__ float skern[4 * KLD];   // skewed gate conv weights
  const int tid = threadIdx.x;
  const int r0 = blockIdx.x * 8;
  const bool first = ((r0 & (LL - 1)) == 0);
  const int lane = tid & 63, wv = tid >> 6;
  const int lm = lane & 15, lq = lane >> 4;
  // chunk offsets row for this block (8 rows always within one 32-row chunk)
  const float* po = part + (size_t)(blockIdx.x >> 2) * ZC;

  // stage z gate cols (1024..2047), rows r0-3 .. r0+7, with skew
  for (int idx = tid; idx < 11 * 128; idx += 256) {
    const int i = idx >> 7, c8 = idx & 127;
    s16x8 v = {0, 0, 0, 0, 0, 0, 0, 0};
    if (!(first && i < 3))
      v = *(const s16x8*)(z + (size_t)(r0 - 3 + i) * ZLD + 1024 + c8 * 8);
    *(s16x8*)&zw[i * GLD + c8 * 8 + (c8 >> 4) * 16] = v;
  }
  // stage gate conv weights (f32) with skew
  for (int idx = tid; idx < 4 * 256; idx += 256) {
    const int w = idx >> 8, c4 = idx & 255;
    float4 v = *(const float4*)(kern + w * ZC + 1024 + c4 * 4);
    *(float4*)&skern[w * KLD + c4 * 4 + (c4 >> 5) * 8] = v;
  }

  // B fragments (same for all rows): lane(lm,lq) holds W'[lq*8+j][nt*16+lm]
  s16x8 bre[2], bim[2];
#pragma unroll
  for (int nt = 0; nt < 2; ++nt)
#pragma unroll
    for (int jj = 0; jj < 8; ++jj) {
      bre[nt][jj] = (short)wp[(lq * 8 + jj) * 32 + nt * 16 + lm];
      bim[nt][jj] = (short)wp[1024 + (lq * 8 + jj) * 32 + nt * 16 + lm];
    }
  __syncthreads();

  const f32x4 z4 = {0.f, 0.f, 0.f, 0.f};
#pragma unroll 1
  for (int rr2 = 0; rr2 < 2; ++rr2) {
    const int rr = wv * 2 + rr2;          // 0..7 within block
    const int bl = r0 + rr;
    float* row = merged + (size_t)bl * ZC;
    // den for BOTH k-halves, before any write to this row (+ chunk offset)
    const float den0 = row[lm] + po[lm];
    const float den1 = row[16 + lm] + po[16 + lm];

#pragma unroll
    for (int khalf = 0; khalf < 2; ++khalf) {
      // A loads: re/im for (bl, k = khalf*16+lm), hp = lq*8..lq*8+7
      const int co = KK + (khalf * 16 + lm) * 32 + lq * 8;
      const float* rp = row + co;
      const float* pp = po + co;
      float4 ra = *(const float4*)rp;
      float4 rb = *(const float4*)(rp + 4);
      float4 ia = *(const float4*)(rp + FLATC);
      float4 ib = *(const float4*)(rp + FLATC + 4);
      float4 qa = *(const float4*)pp;
      float4 qb = *(const float4*)(pp + 4);
      float4 ja = *(const float4*)(pp + FLATC);
      float4 jb = *(const float4*)(pp + FLATC + 4);
      ra.x += qa.x; ra.y += qa.y; ra.z += qa.z; ra.w += qa.w;
      rb.x += qb.x; rb.y += qb.y; rb.z += qb.z; rb.w += qb.w;
      ia.x += ja.x; ia.y += ja.y; ia.z += ja.z; ia.w += ja.w;
      ib.x += jb.x; ib.y += jb.y; ib.z += jb.z; ib.w += jb.w;

      float ssq = ra.x * ra.x + ra.y * ra.y + ra.z * ra.z + ra.w * ra.w +
                  rb.x * rb.x + rb.y * rb.y + rb.z * rb.z + rb.w * rb.w +
                  ia.x * ia.x + ia.y * ia.y + ia.z * ia.z + ia.w * ia.w +
                  ib.x * ib.x + ib.y * ib.y + ib.z * ib.z + ib.w * ib.w;
      ssq += __shfl_xor(ssq, 16);
      ssq += __shfl_xor(ssq, 32);
      const float den = khalf ? den1 : den0;
      const float inv = 1.0f / fmaxf(den, 1e-4f);
      const float scale = inv * rsqrtf(ssq * inv * inv * (1.0f / 64.0f) + 1e-5f);

      s16x8 afr, afi;
      afr[0] = (short)f2bf(ra.x * scale); afr[1] = (short)f2bf(ra.y * scale);
      afr[2] = (short)f2bf(ra.z * scale); afr[3] = (short)f2bf(ra.w * scale);
      afr[4] = (short)f2bf(rb.x * scale); afr[5] = (short)f2bf(rb.y * scale);
      afr[6] = (short)f2bf(rb.z * scale); afr[7] = (short)f2bf(rb.w * scale);
      afi[0] = (short)f2bf(ia.x * scale); afi[1] = (short)f2bf(ia.y * scale);
      afi[2] = (short)f2bf(ia.z * scale); afi[3] = (short)f2bf(ia.w * scale);
      afi[4] = (short)f2bf(ib.x * scale); afi[5] = (short)f2bf(ib.y * scale);
      afi[6] = (short)f2bf(ib.z * scale); afi[7] = (short)f2bf(ib.w * scale);

      f32x4 acc[2];
#pragma unroll
      for (int nt = 0; nt < 2; ++nt) {
        acc[nt] = __builtin_amdgcn_mfma_f32_16x16x32_bf16(afr, bre[nt], z4, 0, 0, 0);
        acc[nt] = __builtin_amdgcn_mfma_f32_16x16x32_bf16(afi, bim[nt], acc[nt], 0, 0, 0);
      }

      // epilogue: D row = lq*4+r (k offset), col = lm (h offset)
      u16* grow = (u16*)row;
#pragma unroll
      for (int nt = 0; nt < 2; ++nt) {
#pragma unroll
        for (int r = 0; r < 4; ++r) {
          const int k = khalf * 16 + lq * 4 + r;
          const int o = k * 32 + nt * 16 + lm;
          const int sk = o + (o >> 7) * 8;    // skern skew
          const int sz = o + (o >> 7) * 16;   // zw skew
          float gv = bf2f(zw[(rr + 0) * GLD + sz]) * skern[0 * KLD + sk];
          gv = fmaf(bf2f(zw[(rr + 1) * GLD + sz]), skern[1 * KLD + sk], gv);
          gv = fmaf(bf2f(zw[(rr + 2) * GLD + sz]), skern[2 * KLD + sk], gv);
          gv = fmaf(bf2f(zw[(rr + 3) * GLD + sz]), skern[3 * KLD + sk], gv);
          const float sil = gv * (1.0f / (1.0f + __expf(-gv)));
          grow[o] = f2bf(acc[nt][r] * sil);
        }
      }
    }
  }
}

// ---------------- launch ----------------
extern "C" void kernel_launch(void* const* d_in, const int* in_sizes, int n_in,
                              void* d_out, int out_size, void* d_ws, size_t ws_size,
                              hipStream_t stream) {
  const float* x      = (const float*)d_in[0];
  const float* W_in   = (const float*)d_in[1];
  const float* kern   = (const float*)d_in[2];
  const float* theta  = (const float*)d_in[3];
  const float* decay  = (const float*)d_in[4];
  const float* anchor = (const float*)d_in[5];
  const float* sscale = (const float*)d_in[6];
  const float* W_re   = (const float*)d_in[7];
  const float* W_im   = (const float*)d_in[8];
  const float* nscale = (const float*)d_in[9];
  const float* W_out  = (const float*)d_in[10];
  float* out = (float*)d_out;

  // workspace layout (~199.3 MiB used; fits the proven 199.75 MiB budget):
  //   merged [136.31 MB] | zbf [68.16 MB] | wp [4 KB] | wbt [4.26 MB] | slack
  // part (512 x 2080 f32 = 4.26 MB) ALIASES wbt: wbt dead after GEMM1,
  // part written by conv_feat_scan afterwards (stream-ordered).
  // transpose_cast(W_in) writes NPAD=2176 rows: rows 2080.. spill into
  // slack after wbt; GEMM1 B-tile 9 reads rows up to 2303 from that slack
  // (garbage, masked by col < Ncols).
  char* w = (char*)d_ws;
  float* merged = (float*)w;
  u16* xbf = (u16*)w;                                  // alias: dead once gemm1 done
  u16* zbf = (u16*)(w + (size_t)BL * ZC * 4);
  u16* wobt = zbf;                                     // alias: written after norm_head
  u16* wp = (u16*)(w + (size_t)BL * ZC * 4 + (size_t)BL * ZLD * 2);
  u16* wbt = wp + 2048;
  float* part = (float*)wbt;                           // alias (see above)

  // 1) casts / transposes / weight fold
  cast_bf16_kernel<<<dim3(BL * DD / 8 / 256), 256, 0, stream>>>(x, xbf, BL * DD);
  transpose_cast_kernel<<<dim3(32, 68), 256, 0, stream>>>(W_in, wbt, DD, ZC, NPAD);
  wprime_kernel<<<dim3(8), 256, 0, stream>>>(W_re, W_im, nscale, wp);

  // 2) GEMM1: z = x @ W_in  (bf16 MFMA, bf16 out). grid.x = row tiles
  // (64 % 8 == 0 -> row stripe pinned to one XCD's L2 across col tiles).
  gemm256_8ph<1><<<dim3(BL / 256, 9), 512, 0, stream>>>(
      xbf, wbt, zbf, DD, DD, ZLD, DD, ZC);

  // 3) conv + p_w + features + chunk-local cumsum -> merged, part
  conv_feat_scan<<<dim3(BL / CCH), 256, 0, stream>>>(
      zbf, kern, theta, decay, anchor, sscale, merged, part);

  // 4) exclusive scan of chunk totals (in-place on part)
  {
    dim3 grid2((ZC + 255) / 256, 1, BB);
    scan_offsets_kernel<<<grid2, 256, 0, stream>>>(part);
  }

  // 5) normalize + RMS + head matmuls (MFMA) + gate -> g (bf16, in-place)
  norm_head_mfma<<<dim3(BL / 8), 256, 0, stream>>>(merged, zbf, kern, wp, part);

  // 6) W_out^T (into dead z region), then GEMM2: out = g @ W_out (f32 out)
  transpose_cast_kernel<<<dim3(32, 32), 256, 0, stream>>>(W_out, wobt, DI, DD, DD);
  gemm256_8ph<0><<<dim3(BL / 256, DD / 256), 512, 0, stream>>>(
      (const u16*)merged, wobt, out, 2 * ZC, DI, DD, DI, DD);
}

// Round 4
// 364.154 us; speedup vs baseline: 1.4289x; 1.0222x over previous
//
#include <hip/hip_runtime.h>
#include <hip/hip_bf16.h>
#include <math.h>

// ---------------- static problem config ----------------
#define BB 4
#define LL 4096
#define DD 1024
#define KK 32
#define HH 32
#define AA 4
#define CKK 4
#define DI 1024
#define ZC 2080            // 2*DI + KK
#define FLATC 1024         // K*H
#define BL (BB * LL)       // 16384
#define ZLD 2080           // z row stride (bf16)
#define NPAD 2176          // W_in^T padded rows (17*128)

// scan config: chunk == conv block == 32 rows
#define CCH 32
#define NCHK (LL / CCH)    // 128 chunks per b

// norm_head LDS strides (skewed to break lq-stride-128 bank conflicts)
#define GLD 1136           // zw row stride in u16 : col = o + (o>>7)*16
#define KLD 1080           // skern row stride in f32: col = o + (o>>7)*8

typedef unsigned short u16;
typedef __attribute__((ext_vector_type(8))) short s16x8;
typedef __attribute__((ext_vector_type(4))) float f32x4;

__device__ __forceinline__ u16 f2bf(float f) {
  union { float f; unsigned int u; } v; v.f = f;
  unsigned int r = (v.u + 0x7FFFu + ((v.u >> 16) & 1u)) >> 16;
  return (u16)r;
}
__device__ __forceinline__ float bf2f(u16 u) {
  union { unsigned int i; float f; } x; x.i = ((unsigned int)u) << 16; return x.f;
}
__device__ __forceinline__ void gl_lds16(const void* g, void* l) {
  __builtin_amdgcn_global_load_lds(
      (const __attribute__((address_space(1))) unsigned int*)g,
      (__attribute__((address_space(3))) unsigned int*)l, 16, 0, 0);
}

// ---------------- cast f32 -> bf16 (x) ----------------
__global__ __launch_bounds__(256) void cast_bf16_kernel(
    const float* __restrict__ src, u16* __restrict__ dst, int n) {
  const int i = (blockIdx.x * 256 + threadIdx.x) * 8;
  if (i >= n) return;
  float4 a = *(const float4*)(src + i);
  float4 b = *(const float4*)(src + i + 4);
  s16x8 v;
  v[0] = (short)f2bf(a.x); v[1] = (short)f2bf(a.y);
  v[2] = (short)f2bf(a.z); v[3] = (short)f2bf(a.w);
  v[4] = (short)f2bf(b.x); v[5] = (short)f2bf(b.y);
  v[6] = (short)f2bf(b.z); v[7] = (short)f2bf(b.w);
  *(s16x8*)(dst + i) = v;
}

// ---------------- transpose + cast: src[R][C] f32 -> dst[Cpad][R] bf16 ----
__global__ __launch_bounds__(256) void transpose_cast_kernel(
    const float* __restrict__ src, u16* __restrict__ dst,
    int R, int C, int Cpad) {
  __shared__ float t[32][33];
  const int tid = threadIdx.x;
  const int r0 = blockIdx.x * 32, c0 = blockIdx.y * 32;
  const int lr = tid >> 5, lc = tid & 31;
#pragma unroll
  for (int i = 0; i < 4; ++i) {
    const int r = r0 + i * 8 + lr, c = c0 + lc;
    float v = 0.f;
    if (r < R && c < C) v = src[(size_t)r * C + c];
    t[lc][i * 8 + lr] = v;
  }
  __syncthreads();
#pragma unroll
  for (int i = 0; i < 4; ++i) {
    const int dr = c0 + i * 8 + lr;   // row in dst = col in src
    const int dc = r0 + lc;           // col in dst = row in src
    if (dr < Cpad && dc < R) dst[(size_t)dr * R + dc] = f2bf(t[i * 8 + lr][lc]);
  }
}

// ---------------- 256x256 8-phase bf16 MFMA GEMM (T1+T2+T3+T4+T5) --------
// C[M,N] = A[M,K] * Bt[N,K]^T.  512 threads = 8 waves (2M x 4N), per-wave
// output 128x64 (8x4 fragments of 16x16), BK=64, NT = K/64 tiles (even).
//
// LDS 128KB: 8 half-regions of 16KB (128 rows x 64 cols bf16, row-major).
// 3-bit XOR swizzle: elem_col ^= (row&7)<<3 (bytes: col ^= (row&7)<<4).
// Per ds_read_b128 the wave's 64 lanes then cover all 8 16B slots with 8
// lanes each = 2 lanes/bank/cycle = conflict-free (G4, m136; verified:
// SQ_LDS_BANK_CONFLICT 7.08M -> 0).
// global_load_lds writes LINEAR dest (dest row&7 == lane>>3), so the
// swizzle is applied by pre-swizzling the GLOBAL source column
// (8*((lane&7)^(lane>>3)) elems); reads apply the same XOR (rule #21).
//
// Stage stream (1 half/phase): p0: s1A1(T2t+1), p1: s0B0(T2t+2),
// p2: s0B1, p3: s0A0, p4: s0A1, p5: s1B0(T2t+3), p6: s1B1, p7: s1A0.
// Gates: s_waitcnt vmcnt(6) at end of p3 and p7 ONLY (3 halves = 6 loads
// allowed in flight).  Raw s_barrier + compiler fence (no __syncthreads,
// so no vmcnt(0) drain) keeps prefetch loads in flight across barriers.
#define FENCE() asm volatile("" ::: "memory")
#define SBAR() do { FENCE(); __builtin_amdgcn_s_barrier(); FENCE(); } while (0)
#define VMCNT6() asm volatile("s_waitcnt vmcnt(6)" ::: "memory")

// region u16 offsets: A(s,h) = (s*2+h)*8192 ; B(s,h) = 32768 + (s*2+h)*8192
#define RA(s, h) (((s) * 2 + (h)) * 8192)
#define RB(s, h) (32768 + ((s) * 2 + (h)) * 8192)

template <int OUT_BF16>
__global__ __launch_bounds__(512, 2) void gemm256_8ph(
    const u16* __restrict__ A, const u16* __restrict__ Bt, void* __restrict__ C,
    int lda, int ldb, int ldc, int Kd, int Ncols) {
  __shared__ u16 lds[65536];   // 128 KiB
  const int tid = threadIdx.x;
  const int lane = tid & 63, wv = tid >> 6;
  const int wm = wv >> 2, wn = wv & 3;       // 2M x 4N wave grid
  const int lm = lane & 15, lq = lane >> 4;
  const int bm = blockIdx.x * 256, bn = blockIdx.y * 256;
  const int NT = Kd >> 6;                    // K tiles (even)
  const int NT2 = NT >> 1;

  // staging: per wave per call, 2x global_load_lds(16B) cover one 16KB
  // half-region (128 rows x 128B). LDS dest linear: row = wv*8+(lane>>3),
  // colbyte = (lane&7)*16. Source col pre-swizzled with the 3-bit XOR:
  const int rofs = wv * 8 + (lane >> 3);                 // region row
  const int cel = ((lane & 7) ^ (lane >> 3)) * 8;        // col elems, swz

  auto stageH = [&](const u16* __restrict__ G, int rowBase, int ld, int kt,
                    int regU16) {
    const u16* g0 = G + (size_t)(rowBase + rofs) * ld + (kt << 6) + cel;
    gl_lds16(g0, &lds[regU16 + wv * 512]);
    const u16* g1 = G + (size_t)(rowBase + 64 + rofs) * ld + (kt << 6) + cel;
    gl_lds16(g1, &lds[regU16 + 4096 + wv * 512]);
  };

  s16x8 Af[4][2], Bf[4][2];
  f32x4 acc[8][4];
  const f32x4 z4 = {0.f, 0.f, 0.f, 0.f};
#pragma unroll
  for (int i = 0; i < 8; ++i)
#pragma unroll
    for (int j = 0; j < 4; ++j) acc[i][j] = z4;

  const int xorw = (lm & 7) << 3;   // read-side swizzle XOR in u16 units

#define DSA(s, mh)                                                          \
  _Pragma("unroll") for (int f = 0; f < 4; ++f)                             \
  _Pragma("unroll") for (int ks = 0; ks < 2; ++ks)                          \
    Af[f][ks] = *(const s16x8*)&lds[RA(s, wm) +                             \
      (((((mh) * 4 + f) * 16 + lm) * 64 + ((ks * 32 + lq * 8) ^ xorw)))];

#define DSB(s)                                                              \
  _Pragma("unroll") for (int f = 0; f < 4; ++f)                             \
  _Pragma("unroll") for (int ks = 0; ks < 2; ++ks)                          \
    Bf[f][ks] = *(const s16x8*)&lds[RB(s, wn >> 1) +                        \
      ((((wn & 1) * 64 + f * 16 + lm) * 64 + ((ks * 32 + lq * 8) ^ xorw)))];

#define QUAD(mh, nh)                                                        \
  do {                                                                      \
    __builtin_amdgcn_s_setprio(1);                                          \
    _Pragma("unroll") for (int f = 0; f < 4; ++f)                           \
    _Pragma("unroll") for (int n = 0; n < 2; ++n)                           \
    _Pragma("unroll") for (int ks = 0; ks < 2; ++ks)                        \
      acc[(mh) * 4 + f][(nh) * 2 + n] =                                     \
          __builtin_amdgcn_mfma_f32_16x16x32_bf16(                          \
              Af[f][ks], Bf[(nh) * 2 + n][ks],                              \
              acc[(mh) * 4 + f][(nh) * 2 + n], 0, 0, 0);                    \
    __builtin_amdgcn_s_setprio(0);                                          \
  } while (0)

  // ---- prologue: 7 halves (t0 full + t1 B0,B1,A0); t1A1 comes at p0 ----
  stageH(A, bm, lda, 0, RA(0, 0));
  stageH(A, bm + 128, lda, 0, RA(0, 1));
  stageH(Bt, bn, ldb, 0, RB(0, 0));
  stageH(Bt, bn + 128, ldb, 0, RB(0, 1));
  stageH(Bt, bn, ldb, 1, RB(1, 0));
  stageH(Bt, bn + 128, ldb, 1, RB(1, 1));
  stageH(A, bm, lda, 1, RA(1, 0));
  VMCNT6();        // first 4 halves (tile 0) landed
  SBAR();

#pragma unroll 1
  for (int t = 0; t < NT2; ++t) {
    const int T2 = 2 * t + 2, T3 = 2 * t + 3;
    // -------- tile 2t from slot 0 --------
    // p0
    DSA(0, 0); DSB(0);
    stageH(A, bm + 128, lda, 2 * t + 1, RA(1, 1));   // s1A1 of tile 2t+1
    SBAR();
    QUAD(0, 0);
    SBAR();
    // p1
    if (T2 < NT) stageH(Bt, bn, ldb, T2, RB(0, 0));
    SBAR();
    QUAD(0, 1);
    SBAR();
    // p2
    DSA(0, 1);
    if (T2 < NT) stageH(Bt, bn + 128, ldb, T2, RB(0, 1));
    SBAR();
    QUAD(1, 0);
    SBAR();
    // p3
    if (T2 < NT) stageH(A, bm, lda, T2, RA(0, 0));
    SBAR();
    QUAD(1, 1);
    VMCNT6();      // slot1 (tile 2t+1) fully landed before p4 reads
    SBAR();
    // -------- tile 2t+1 from slot 1 --------
    // p4
    DSA(1, 0); DSB(1);
    if (T2 < NT) stageH(A, bm + 128, lda, T2, RA(0, 1));
    SBAR();
    QUAD(0, 0);
    SBAR();
    // p5
    if (T3 < NT) stageH(Bt, bn, ldb, T3, RB(1, 0));
    SBAR();
    QUAD(0, 1);
    SBAR();
    // p6
    DSA(1, 1);
    if (T3 < NT) stageH(Bt, bn + 128, ldb, T3, RB(1, 1));
    SBAR();
    QUAD(1, 0);
    SBAR();
    // p7
    if (T3 < NT) stageH(A, bm, lda, T3, RA(1, 0));
    SBAR();
    QUAD(1, 1);
    VMCNT6();      // slot0 (tile 2t+2) fully landed before next p0 reads
    SBAR();
  }

  // epilogue: D col = lm, row = lq*4 + r within each 16x16 fragment
#pragma unroll
  for (int f = 0; f < 8; ++f) {
#pragma unroll
    for (int n = 0; n < 4; ++n) {
#pragma unroll
      for (int r = 0; r < 4; ++r) {
        const int row = bm + wm * 128 + f * 16 + lq * 4 + r;
        const int col = bn + wn * 64 + n * 16 + lm;
        if (col < Ncols) {
          if (OUT_BF16)
            ((u16*)C)[(size_t)row * ldc + col] = f2bf(acc[f][n][r]);
          else
            ((float*)C)[(size_t)row * ldc + col] = acc[f][n][r];
        }
      }
    }
  }
#undef DSA
#undef DSB
#undef QUAD
}

// ---------------- score GEMM: z[:,2048:2080] = x @ W_in[:,2048:2080] -----
// Tiny (16384x32x1024 = 1.07 GFLOP). 128-row blocks x 32 cols, 4 waves
// (wave wv -> rows wv*32..+31, 2 m-frags x 2 n-frags), BK=64, simple
// 2-barrier loop with global_load_lds staging. Removes the 9th (224-col
// garbage) tile from the main GEMM so its grid is 512 = 2 clean rounds.
__global__ __launch_bounds__(256) void score_gemm(
    const u16* __restrict__ A, const u16* __restrict__ Bt,
    u16* __restrict__ z) {
  __shared__ u16 As[8192];   // 16 units x 512 elems (128 rows x 64 k)
  __shared__ u16 Bs[2048];   // 4 units  (32 rows x 64 k)
  const int tid = threadIdx.x;
  const int lane = tid & 63, wv = tid >> 6;
  const int lm = lane & 15, lq = lane >> 4;
  const int bm = blockIdx.x * 128;

  const f32x4 z4 = {0.f, 0.f, 0.f, 0.f};
  f32x4 acc[2][2];
#pragma unroll
  for (int i = 0; i < 2; ++i)
#pragma unroll
    for (int j = 0; j < 2; ++j) acc[i][j] = z4;

  for (int k0 = 0; k0 < DD; k0 += 64) {
    __syncthreads();
#pragma unroll
    for (int t = 0; t < 5; ++t) {
      const int idx = wv * 5 + t;            // 0..19
      if (idx < 16) {                        // A unit (mt, kt)
        const int mt = idx >> 1, kt = idx & 1;
        const u16* g = A + (size_t)(bm + mt * 16 + lm) * DD + k0 + kt * 32 + lq * 8;
        gl_lds16(g, &As[idx * 512]);
      } else {                               // B unit (nt, kt)
        const int bidx = idx - 16;
        const int nt = bidx >> 1, kt = bidx & 1;
        const u16* g = Bt + (size_t)(2048 + nt * 16 + lm) * DD + k0 + kt * 32 + lq * 8;
        gl_lds16(g, &Bs[bidx * 512]);
      }
    }
    __syncthreads();
#pragma unroll
    for (int kt = 0; kt < 2; ++kt) {
      s16x8 af[2], bfb[2];
#pragma unroll
      for (int i = 0; i < 2; ++i) {
        const int mt = wv * 2 + i;
        af[i] = *(const s16x8*)&As[(mt * 2 + kt) * 512 + lane * 8];
        bfb[i] = *(const s16x8*)&Bs[(i * 2 + kt) * 512 + lane * 8];
      }
#pragma unroll
      for (int i = 0; i < 2; ++i)
#pragma unroll
        for (int j = 0; j < 2; ++j)
          acc[i][j] = __builtin_amdgcn_mfma_f32_16x16x32_bf16(af[i], bfb[j], acc[i][j], 0, 0, 0);
    }
  }
#pragma unroll
  for (int i = 0; i < 2; ++i)
#pragma unroll
    for (int j = 0; j < 2; ++j)
#pragma unroll
      for (int r = 0; r < 4; ++r) {
        const int row = bm + wv * 32 + i * 16 + lq * 4 + r;
        const int col = 2048 + j * 16 + lm;
        z[(size_t)row * ZLD + col] = f2bf(acc[i][j][r]);
      }
}

// ---------------- conv + p_w + features + chunk-local cumsum --------------
// One block = one 32-row chunk. Features are computed with a rolling
// 4-deep z history in registers and accumulated into a chunk-local
// inclusive cumsum (registers, while values are live); the chunk total
// goes to part[chunk]. This deletes the scan_partial (136 MB read) and
// scan_apply (272 MB r+w) passes entirely.
__global__ __launch_bounds__(256) void conv_feat_scan(
    const u16* __restrict__ z, const float* __restrict__ kern,
    const float* __restrict__ theta, const float* __restrict__ decay,
    const float* __restrict__ anchor, const float* __restrict__ sscale,
    float* __restrict__ merged, float* __restrict__ part) {
  __shared__ float pbuf[CCH][KK];   // raw p_w per (row, head)
  const int tid = threadIdx.x;
  const int r0 = blockIdx.x * CCH;           // global row base
  const bool first = ((r0 & (LL - 1)) == 0);
  const int chunk = blockIdx.x;              // global chunk id

  // phase A: p_w for 32 rows x 32 heads (4 items/thread)
#pragma unroll
  for (int q = 0; q < 4; ++q) {
    const int item = q * 256 + tid;
    const int row = item >> 5, k = item & 31;
    float v = 0.f;
#pragma unroll
    for (int w = 0; w < CKK; ++w) {
      const int g = row + w;                 // offset from r0-3
      float zv = 0.f;
      if (!(first && g < 3))
        zv = bf2f(z[(size_t)(r0 - 3 + g) * ZLD + 2048 + k]);
      v = fmaf(zv, kern[w * ZC + 2048 + k], v);
    }
    const int l = (r0 + row) & (LL - 1);
    const float slope = (k < KK - AA) ? decay[k] : anchor[k - (KK - AA)];
    const float sp = log1pf(__expf(slope));
    const float lw = (k < KK - AA) ? (-sp * (float)(LL - 1 - l)) : (-sp * (float)l);
    pbuf[row][k] = __expf(sscale[k] * v + lw);
  }
  __syncthreads();

  // phase B: den chunk-local cumsum (32 threads; LDS reads conflict-free)
  if (tid < KK) {
    float run = 0.f;
#pragma unroll
    for (int row = 0; row < CCH; ++row) {
      run += pbuf[row][tid];
      merged[(size_t)(r0 + row) * ZC + tid] = run;
    }
    part[(size_t)chunk * ZC + tid] = run;
  }

  // phase C: features + chunk-local cumsum (reads pbuf raw, no extra sync
  // needed: phase B wrote only global memory)
#pragma unroll 1
  for (int it = 0; it < 4; ++it) {
    const int c = it * 256 + tid;            // 0..1023
    const float kw0 = kern[0 * ZC + c], kw1 = kern[1 * ZC + c];
    const float kw2 = kern[2 * ZC + c], kw3 = kern[3 * ZC + c];
    const float th = theta[c];
    const int head = c >> 5;
    float h0 = 0.f, h1 = 0.f, h2 = 0.f;      // rolling z history
    if (!first) {
      h0 = bf2f(z[(size_t)(r0 - 3) * ZLD + c]);
      h1 = bf2f(z[(size_t)(r0 - 2) * ZLD + c]);
      h2 = bf2f(z[(size_t)(r0 - 1) * ZLD + c]);
    }
    float sre = 0.f, sim = 0.f;
#pragma unroll 4
    for (int row = 0; row < CCH; ++row) {
      const float h3 = bf2f(z[(size_t)(r0 + row) * ZLD + c]);
      float v = h0 * kw0;
      v = fmaf(h1, kw1, v);
      v = fmaf(h2, kw2, v);
      v = fmaf(h3, kw3, v);
      h0 = h1; h1 = h2; h2 = h3;
      const float phi = v * th;
      float sv, cv;
      __sincosf(phi, &sv, &cv);
      const float p = pbuf[row][head];
      sre = fmaf(p, cv, sre);
      sim = fmaf(p, sv, sim);
      float* mrow = merged + (size_t)(r0 + row) * ZC;
      mrow[KK + c] = sre;
      mrow[KK + FLATC + c] = sim;
    }
    part[(size_t)chunk * ZC + KK + c] = sre;
    part[(size_t)chunk * ZC + KK + FLATC + c] = sim;
  }
}

// ---------------- exclusive scan of chunk totals (128 chunks per b) -------
__global__ __launch_bounds__(256) void scan_offsets_kernel(float* __restrict__ part) {
  const int c = blockIdx.x * 256 + threadIdx.x;
  const int b = blockIdx.z;
  if (c >= ZC) return;
  float run = 0.f;
#pragma unroll 8
  for (int i = 0; i < NCHK; ++i) {
    const size_t idx = ((size_t)b * NCHK + i) * ZC + c;
    const float t = part[idx];
    part[idx] = run;
    run += t;
  }
}

// ---------------- fold norm_scale into head weights (bf16) ----------------
__global__ __launch_bounds__(256) void wprime_kernel(
    const float* __restrict__ W_re, const float* __restrict__ W_im,
    const float* __restrict__ ns, u16* __restrict__ wp) {
  const int i = blockIdx.x * 256 + threadIdx.x;   // 0..2047
  if (i < 1024) wp[i] = f2bf(ns[i >> 5] * W_re[i]);
  else {
    const int j = i - 1024;
    wp[i] = f2bf(ns[32 + (j >> 5)] * W_im[j]);
  }
}

// ---------------- norm_head via MFMA ----------------
// Block = 8 bl rows (4 waves x 2 rows). merged holds CHUNK-LOCAL cumsum;
// the global prefix is chunk-local + part[chunk] (exclusive offsets),
// added at load time (den and re/im). Per (bl,k) row: scale from raw row
// sums, y = [re;im]*scale @ [Wre';Wim'] via 16x16x32 bf16 MFMA, g = y*gate
// written bf16 in-place into merged row head (den read before any write).
__global__ __launch_bounds__(256) void norm_head_mfma(
    float* merged, const u16* __restrict__ z, const float* __restrict__ kern,
    const u16* __restrict__ wp, const float* __restrict__ part) {
  __shared__ u16 zw[11 * GLD];       // skewed gate-z tile
  __shared__ float skern[4 * KLD];   // skewed gate conv weights
  const int tid = threadIdx.x;
  const int r0 = blockIdx.x * 8;
  const bool first = ((r0 & (LL - 1)) == 0);
  const int lane = tid & 63, wv = tid >> 6;
  const int lm = lane & 15, lq = lane >> 4;
  // chunk offsets row for this block (8 rows always within one 32-row chunk)
  const float* po = part + (size_t)(blockIdx.x >> 2) * ZC;

  // stage z gate cols (1024..2047), rows r0-3 .. r0+7, with skew
  for (int idx = tid; idx < 11 * 128; idx += 256) {
    const int i = idx >> 7, c8 = idx & 127;
    s16x8 v = {0, 0, 0, 0, 0, 0, 0, 0};
    if (!(first && i < 3))
      v = *(const s16x8*)(z + (size_t)(r0 - 3 + i) * ZLD + 1024 + c8 * 8);
    *(s16x8*)&zw[i * GLD + c8 * 8 + (c8 >> 4) * 16] = v;
  }
  // stage gate conv weights (f32) with skew
  for (int idx = tid; idx < 4 * 256; idx += 256) {
    const int w = idx >> 8, c4 = idx & 255;
    float4 v = *(const float4*)(kern + w * ZC + 1024 + c4 * 4);
    *(float4*)&skern[w * KLD + c4 * 4 + (c4 >> 5) * 8] = v;
  }

  // B fragments (same for all rows): lane(lm,lq) holds W'[lq*8+j][nt*16+lm]
  s16x8 bre[2], bim[2];
#pragma unroll
  for (int nt = 0; nt < 2; ++nt)
#pragma unroll
    for (int jj = 0; jj < 8; ++jj) {
      bre[nt][jj] = (short)wp[(lq * 8 + jj) * 32 + nt * 16 + lm];
      bim[nt][jj] = (short)wp[1024 + (lq * 8 + jj) * 32 + nt * 16 + lm];
    }
  __syncthreads();

  const f32x4 z4 = {0.f, 0.f, 0.f, 0.f};
#pragma unroll 1
  for (int rr2 = 0; rr2 < 2; ++rr2) {
    const int rr = wv * 2 + rr2;          // 0..7 within block
    const int bl = r0 + rr;
    float* row = merged + (size_t)bl * ZC;
    // den for BOTH k-halves, before any write to this row (+ chunk offset)
    const float den0 = row[lm] + po[lm];
    const float den1 = row[16 + lm] + po[16 + lm];

#pragma unroll
    for (int khalf = 0; khalf < 2; ++khalf) {
      // A loads: re/im for (bl, k = khalf*16+lm), hp = lq*8..lq*8+7
      const int co = KK + (khalf * 16 + lm) * 32 + lq * 8;
      const float* rp = row + co;
      const float* pp = po + co;
      float4 ra = *(const float4*)rp;
      float4 rb = *(const float4*)(rp + 4);
      float4 ia = *(const float4*)(rp + FLATC);
      float4 ib = *(const float4*)(rp + FLATC + 4);
      float4 qa = *(const float4*)pp;
      float4 qb = *(const float4*)(pp + 4);
      float4 ja = *(const float4*)(pp + FLATC);
      float4 jb = *(const float4*)(pp + FLATC + 4);
      ra.x += qa.x; ra.y += qa.y; ra.z += qa.z; ra.w += qa.w;
      rb.x += qb.x; rb.y += qb.y; rb.z += qb.z; rb.w += qb.w;
      ia.x += ja.x; ia.y += ja.y; ia.z += ja.z; ia.w += ja.w;
      ib.x += jb.x; ib.y += jb.y; ib.z += jb.z; ib.w += jb.w;

      float ssq = ra.x * ra.x + ra.y * ra.y + ra.z * ra.z + ra.w * ra.w +
                  rb.x * rb.x + rb.y * rb.y + rb.z * rb.z + rb.w * rb.w +
                  ia.x * ia.x + ia.y * ia.y + ia.z * ia.z + ia.w * ia.w +
                  ib.x * ib.x + ib.y * ib.y + ib.z * ib.z + ib.w * ib.w;
      ssq += __shfl_xor(ssq, 16);
      ssq += __shfl_xor(ssq, 32);
      const float den = khalf ? den1 : den0;
      const float inv = 1.0f / fmaxf(den, 1e-4f);
      const float scale = inv * rsqrtf(ssq * inv * inv * (1.0f / 64.0f) + 1e-5f);

      s16x8 afr, afi;
      afr[0] = (short)f2bf(ra.x * scale); afr[1] = (short)f2bf(ra.y * scale);
      afr[2] = (short)f2bf(ra.z * scale); afr[3] = (short)f2bf(ra.w * scale);
      afr[4] = (short)f2bf(rb.x * scale); afr[5] = (short)f2bf(rb.y * scale);
      afr[6] = (short)f2bf(rb.z * scale); afr[7] = (short)f2bf(rb.w * scale);
      afi[0] = (short)f2bf(ia.x * scale); afi[1] = (short)f2bf(ia.y * scale);
      afi[2] = (short)f2bf(ia.z * scale); afi[3] = (short)f2bf(ia.w * scale);
      afi[4] = (short)f2bf(ib.x * scale); afi[5] = (short)f2bf(ib.y * scale);
      afi[6] = (short)f2bf(ib.z * scale); afi[7] = (short)f2bf(ib.w * scale);

      f32x4 acc[2];
#pragma unroll
      for (int nt = 0; nt < 2; ++nt) {
        acc[nt] = __builtin_amdgcn_mfma_f32_16x16x32_bf16(afr, bre[nt], z4, 0, 0, 0);
        acc[nt] = __builtin_amdgcn_mfma_f32_16x16x32_bf16(afi, bim[nt], acc[nt], 0, 0, 0);
      }

      // epilogue: D row = lq*4+r (k offset), col = lm (h offset)
      u16* grow = (u16*)row;
#pragma unroll
      for (int nt = 0; nt < 2; ++nt) {
#pragma unroll
        for (int r = 0; r < 4; ++r) {
          const int k = khalf * 16 + lq * 4 + r;
          const int o = k * 32 + nt * 16 + lm;
          const int sk = o + (o >> 7) * 8;    // skern skew
          const int sz = o + (o >> 7) * 16;   // zw skew
          float gv = bf2f(zw[(rr + 0) * GLD + sz]) * skern[0 * KLD + sk];
          gv = fmaf(bf2f(zw[(rr + 1) * GLD + sz]), skern[1 * KLD + sk], gv);
          gv = fmaf(bf2f(zw[(rr + 2) * GLD + sz]), skern[2 * KLD + sk], gv);
          gv = fmaf(bf2f(zw[(rr + 3) * GLD + sz]), skern[3 * KLD + sk], gv);
          const float sil = gv * (1.0f / (1.0f + __expf(-gv)));
          grow[o] = f2bf(acc[nt][r] * sil);
        }
      }
    }
  }
}

// ---------------- launch ----------------
extern "C" void kernel_launch(void* const* d_in, const int* in_sizes, int n_in,
                              void* d_out, int out_size, void* d_ws, size_t ws_size,
                              hipStream_t stream) {
  const float* x      = (const float*)d_in[0];
  const float* W_in   = (const float*)d_in[1];
  const float* kern   = (const float*)d_in[2];
  const float* theta  = (const float*)d_in[3];
  const float* decay  = (const float*)d_in[4];
  const float* anchor = (const float*)d_in[5];
  const float* sscale = (const float*)d_in[6];
  const float* W_re   = (const float*)d_in[7];
  const float* W_im   = (const float*)d_in[8];
  const float* nscale = (const float*)d_in[9];
  const float* W_out  = (const float*)d_in[10];
  float* out = (float*)d_out;

  // workspace layout (~199.3 MiB used; fits the proven 199.75 MiB budget):
  //   merged [136.31 MB] | zbf [68.16 MB] | wp [4 KB] | wbt [4.26 MB] | slack
  // part (512 x 2080 f32 = 4.26 MB) ALIASES wbt: wbt dead after GEMM1+
  // score_gemm, part written by conv_feat_scan afterwards (stream-ordered).
  // transpose_cast(W_in) writes NPAD=2176 rows (2080..2175 zero-pad).
  char* w = (char*)d_ws;
  float* merged = (float*)w;
  u16* xbf = (u16*)w;                                  // alias: dead once gemm1 done
  u16* zbf = (u16*)(w + (size_t)BL * ZC * 4);
  u16* wobt = zbf;                                     // alias: written after norm_head
  u16* wp = (u16*)(w + (size_t)BL * ZC * 4 + (size_t)BL * ZLD * 2);
  u16* wbt = wp + 2048;
  float* part = (float*)wbt;                           // alias (see above)

  // 1) casts / transposes / weight fold
  cast_bf16_kernel<<<dim3(BL * DD / 8 / 256), 256, 0, stream>>>(x, xbf, BL * DD);
  transpose_cast_kernel<<<dim3(32, 68), 256, 0, stream>>>(W_in, wbt, DD, ZC, NPAD);
  wprime_kernel<<<dim3(8), 256, 0, stream>>>(W_re, W_im, nscale, wp);

  // 2a) score cols 2048..2079 of z (tiny GEMM, removes the 9th col tile)
  score_gemm<<<dim3(BL / 128), 256, 0, stream>>>(xbf, wbt, zbf);

  // 2b) GEMM1 main: z[:, :2048] = x @ W_in[:, :2048]. grid = 64x8 = 512
  // blocks = exactly 2 clean dispatch rounds at 1 block/CU (no 64-block
  // tail round, no pad columns). grid.x = row tiles (x%8 -> XCD pinning
  // of the A row stripe across col tiles).
  gemm256_8ph<1><<<dim3(BL / 256, 8), 512, 0, stream>>>(
      xbf, wbt, zbf, DD, DD, ZLD, DD, ZC);

  // 3) conv + p_w + features + chunk-local cumsum -> merged, part
  conv_feat_scan<<<dim3(BL / CCH), 256, 0, stream>>>(
      zbf, kern, theta, decay, anchor, sscale, merged, part);

  // 4) exclusive scan of chunk totals (in-place on part)
  {
    dim3 grid2((ZC + 255) / 256, 1, BB);
    scan_offsets_kernel<<<grid2, 256, 0, stream>>>(part);
  }

  // 5) normalize + RMS + head matmuls (MFMA) + gate -> g (bf16, in-place)
  norm_head_mfma<<<dim3(BL / 8), 256, 0, stream>>>(merged, zbf, kern, wp, part);

  // 6) W_out^T (into dead z region), then GEMM2: out = g @ W_out (f32 out)
  transpose_cast_kernel<<<dim3(32, 32), 256, 0, stream>>>(W_out, wobt, DI, DD, DD);
  gemm256_8ph<0><<<dim3(BL / 256, DD / 256), 512, 0, stream>>>(
      (const u16*)merged, wobt, out, 2 * ZC, DI, DD, DI, DD);
}